// Round 15
// baseline (285.918 us; speedup 1.0000x reference)
//
#include <hip/hip_runtime.h>
#include <hip/hip_bf16.h>
#include <math.h>

#define NN 50000
#define NE 800000
#define DIN 128
#define DHID 128
#define DOUT 64
#define BN_EPS 1e-5f

typedef __attribute__((ext_vector_type(8))) short bf16x8;
typedef __attribute__((ext_vector_type(8))) _Float16 f16x8;
typedef __attribute__((ext_vector_type(4))) _Float16 f16x4;
typedef __attribute__((ext_vector_type(2))) _Float16 f16x2;
typedef __attribute__((ext_vector_type(4))) float f32x4;
typedef unsigned short ushort_t;
typedef unsigned int uint_t;

__device__ __forceinline__ ushort_t f2bf(float f) {
    uint_t u = __float_as_uint(f);
    uint_t r = (u + 0x7FFFu + ((u >> 16) & 1u)) >> 16;   // RNE
    return (ushort_t)r;
}

__device__ __forceinline__ uint_t pk2bf(float a, float b) {
    __hip_bfloat16 x = __float2bfloat16(a);
    __hip_bfloat16 y = __float2bfloat16(b);
    ushort_t ux = *reinterpret_cast<ushort_t*>(&x);
    ushort_t uy = *reinterpret_cast<ushort_t*>(&y);
    return (uint_t)ux | ((uint_t)uy << 16);
}

// ---------------------------------------------------------------------------
// Fused: blocks [0,3125) histogram dst degrees; blocks [3125,6250) cast x->fp16.
__global__ __launch_bounds__(256) void k_deg_xcast(
    const int* __restrict__ ei, int* __restrict__ deg,
    const float* __restrict__ x, _Float16* __restrict__ xh)
{
    int b = blockIdx.x;
    if (b < 3125) {
        int e = b * 256 + threadIdx.x;
        atomicAdd(deg + ei[NE + e], 1);
    } else {
        int i = (b - 3125) * 256 + threadIdx.x;
        const float4* src = (const float4*)x + (size_t)i * 2;
        float4 a = src[0], c = src[1];
        f16x8 o;
        o[0] = (_Float16)a.x; o[1] = (_Float16)a.y; o[2] = (_Float16)a.z; o[3] = (_Float16)a.w;
        o[4] = (_Float16)c.x; o[5] = (_Float16)c.y; o[6] = (_Float16)c.z; o[7] = (_Float16)c.w;
        *(f16x8*)(xh + (size_t)i * 8) = o;
    }
}

// ---------------------------------------------------------------------------
// Scan stage 1 (blocks 0..48) + weight prep (block 49).
__global__ __launch_bounds__(256) void k_scan1_prep(
    const int* __restrict__ deg, int* __restrict__ part,
    const float* __restrict__ c1_Wl, const float* __restrict__ c1_Wr,
    const float* __restrict__ c2_Wl, const float* __restrict__ c2_Wr,
    const float* __restrict__ gam, const float* __restrict__ bet,
    const float* __restrict__ bmean, const float* __restrict__ bvar,
    const float* __restrict__ eW1, const float* __restrict__ eW2,
    _Float16* __restrict__ w1cat, _Float16* __restrict__ w2cat,
    ushort_t* __restrict__ w1bf, ushort_t* __restrict__ w2bf,
    float* __restrict__ bnsc, float* __restrict__ bnsh)
{
    int t = threadIdx.x;
    if (blockIdx.x < 49) {
        __shared__ int s[256];
        int g = blockIdx.x * 256 + t;
        int v = 0;
        if (g < 12500) { int4 d = ((const int4*)deg)[g]; v = d.x + d.y + d.z + d.w; }
        s[t] = v;
        __syncthreads();
        #pragma unroll
        for (int off = 128; off > 0; off >>= 1) {
            if (t < off) s[t] += s[t + off];
            __syncthreads();
        }
        if (t == 0) part[blockIdx.x] = s[0];
    } else {
        for (int i = t; i < 128 * 128; i += 256) {
            int row = i >> 7, k = i & 127;
            w1cat[row * 256 + k]       = (_Float16)c1_Wl[i];
            w1cat[row * 256 + 128 + k] = (_Float16)c1_Wr[i];
        }
        for (int i = t; i < 64 * 128; i += 256) {
            int row = i >> 7, k = i & 127;
            w2cat[row * 256 + k]       = (_Float16)c2_Wl[i];
            w2cat[row * 256 + 128 + k] = (_Float16)c2_Wr[i];
        }
        for (int i = t; i < 64 * 128; i += 256) w1bf[i] = f2bf(eW1[i]);
        for (int i = t; i < 32 * 64; i += 256)  w2bf[i] = f2bf(eW2[i]);
        for (int i = t; i < 128; i += 256) {
            float s = gam[i] * rsqrtf(bvar[i] + BN_EPS);
            bnsc[i] = s;
            bnsh[i] = bet[i] - bmean[i] * s;
        }
    }
}

// Scan stage 2: per-block exclusive scan + block offset.
__global__ __launch_bounds__(256) void k_scan3(
    const int* __restrict__ deg, const int* __restrict__ part, int* __restrict__ rowptr)
{
    __shared__ int s[256];
    __shared__ int p[64];
    int t = threadIdx.x;
    int b = blockIdx.x;
    int g = b * 256 + t;
    int4 d = make_int4(0, 0, 0, 0);
    if (g < 12500) d = ((const int4*)deg)[g];
    int sum4 = d.x + d.y + d.z + d.w;
    s[t] = sum4;
    if (t < 49) p[t] = part[t];
    __syncthreads();
    #pragma unroll
    for (int off = 1; off < 256; off <<= 1) {
        int v = (t >= off) ? s[t - off] : 0;
        __syncthreads();
        s[t] += v;
        __syncthreads();
    }
    int blockoff = 0;
    for (int i = 0; i < b; ++i) blockoff += p[i];
    int off0 = blockoff + s[t] - sum4;
    if (g < 12500) {
        int4 o;
        o.x = off0;
        o.y = off0 + d.x;
        o.z = o.y + d.y;
        o.w = o.z + d.z;
        ((int4*)rowptr)[g] = o;
        if (g == 12499) rowptr[NN] = o.w + d.w;
    }
}

// Fill CSR column (src) array.
__global__ __launch_bounds__(256) void k_fill(
    const int* __restrict__ ei, const int* __restrict__ rowptr,
    int* __restrict__ cursor, int* __restrict__ csr_src)
{
    int e = blockIdx.x * blockDim.x + threadIdx.x;
    if (e >= NE) return;
    int dst = ei[NE + e];
    int slot = atomicAdd(cursor + dst, 1);
    csr_src[rowptr[dst] + slot] = ei[e];
}

// ---------------------------------------------------------------------------
// 128-dim gather: wave gathers 4 nodes' means into swizzled LDS. Main loop:
// 16 independent row loads in flight (all issued before first accumulate).
#define GATHER4_128(feat)                                                      \
    {                                                                          \
        _Pragma("unroll 1")                                                    \
        for (int q = 0; q < 4; ++q) {                                          \
            int n = w * 4 + q;                                                 \
            int node4 = tile * 16 + n;                                         \
            int beg = __builtin_amdgcn_readfirstlane(rowptr[node4]);           \
            int end = __builtin_amdgcn_readfirstlane(rowptr[node4 + 1]);       \
            float2 a0 = {0.f,0.f}, a1 = {0.f,0.f}, a2 = {0.f,0.f}, a3 = {0.f,0.f}; \
            float2 a4 = {0.f,0.f}, a5 = {0.f,0.f}, a6 = {0.f,0.f}, a7 = {0.f,0.f}; \
            int j = beg;                                                       \
            for (; j + 15 < end; j += 16) {                                    \
                int s0 = csr_src[j];      int s1 = csr_src[j + 1];             \
                int s2 = csr_src[j + 2];  int s3 = csr_src[j + 3];             \
                int s4 = csr_src[j + 4];  int s5 = csr_src[j + 5];             \
                int s6 = csr_src[j + 6];  int s7 = csr_src[j + 7];             \
                int s8 = csr_src[j + 8];  int s9 = csr_src[j + 9];             \
                int sa = csr_src[j + 10]; int sb = csr_src[j + 11];            \
                int sc = csr_src[j + 12]; int sd = csr_src[j + 13];            \
                int se = csr_src[j + 14]; int sf = csr_src[j + 15];            \
                f16x2 v0 = *(const f16x2*)(feat + (size_t)s0 * 128 + lane * 2);\
                f16x2 v1 = *(const f16x2*)(feat + (size_t)s1 * 128 + lane * 2);\
                f16x2 v2 = *(const f16x2*)(feat + (size_t)s2 * 128 + lane * 2);\
                f16x2 v3 = *(const f16x2*)(feat + (size_t)s3 * 128 + lane * 2);\
                f16x2 v4 = *(const f16x2*)(feat + (size_t)s4 * 128 + lane * 2);\
                f16x2 v5 = *(const f16x2*)(feat + (size_t)s5 * 128 + lane * 2);\
                f16x2 v6 = *(const f16x2*)(feat + (size_t)s6 * 128 + lane * 2);\
                f16x2 v7 = *(const f16x2*)(feat + (size_t)s7 * 128 + lane * 2);\
                f16x2 v8 = *(const f16x2*)(feat + (size_t)s8 * 128 + lane * 2);\
                f16x2 v9 = *(const f16x2*)(feat + (size_t)s9 * 128 + lane * 2);\
                f16x2 va = *(const f16x2*)(feat + (size_t)sa * 128 + lane * 2);\
                f16x2 vb = *(const f16x2*)(feat + (size_t)sb * 128 + lane * 2);\
                f16x2 vc = *(const f16x2*)(feat + (size_t)sc * 128 + lane * 2);\
                f16x2 vd = *(const f16x2*)(feat + (size_t)sd * 128 + lane * 2);\
                f16x2 ve = *(const f16x2*)(feat + (size_t)se * 128 + lane * 2);\
                f16x2 vf = *(const f16x2*)(feat + (size_t)sf * 128 + lane * 2);\
                a0.x += (float)v0[0] + (float)v8[0]; a0.y += (float)v0[1] + (float)v8[1]; \
                a1.x += (float)v1[0] + (float)v9[0]; a1.y += (float)v1[1] + (float)v9[1]; \
                a2.x += (float)v2[0] + (float)va[0]; a2.y += (float)v2[1] + (float)va[1]; \
                a3.x += (float)v3[0] + (float)vb[0]; a3.y += (float)v3[1] + (float)vb[1]; \
                a4.x += (float)v4[0] + (float)vc[0]; a4.y += (float)v4[1] + (float)vc[1]; \
                a5.x += (float)v5[0] + (float)vd[0]; a5.y += (float)v5[1] + (float)vd[1]; \
                a6.x += (float)v6[0] + (float)ve[0]; a6.y += (float)v6[1] + (float)ve[1]; \
                a7.x += (float)v7[0] + (float)vf[0]; a7.y += (float)v7[1] + (float)vf[1]; \
            }                                                                  \
            if (j + 7 < end) {                                                 \
                int s0 = csr_src[j];     int s1 = csr_src[j + 1];              \
                int s2 = csr_src[j + 2]; int s3 = csr_src[j + 3];              \
                int s4 = csr_src[j + 4]; int s5 = csr_src[j + 5];              \
                int s6 = csr_src[j + 6]; int s7 = csr_src[j + 7];              \
                f16x2 v0 = *(const f16x2*)(feat + (size_t)s0 * 128 + lane * 2);\
                f16x2 v1 = *(const f16x2*)(feat + (size_t)s1 * 128 + lane * 2);\
                f16x2 v2 = *(const f16x2*)(feat + (size_t)s2 * 128 + lane * 2);\
                f16x2 v3 = *(const f16x2*)(feat + (size_t)s3 * 128 + lane * 2);\
                f16x2 v4 = *(const f16x2*)(feat + (size_t)s4 * 128 + lane * 2);\
                f16x2 v5 = *(const f16x2*)(feat + (size_t)s5 * 128 + lane * 2);\
                f16x2 v6 = *(const f16x2*)(feat + (size_t)s6 * 128 + lane * 2);\
                f16x2 v7 = *(const f16x2*)(feat + (size_t)s7 * 128 + lane * 2);\
                a0.x += (float)v0[0]; a0.y += (float)v0[1];                    \
                a1.x += (float)v1[0]; a1.y += (float)v1[1];                    \
                a2.x += (float)v2[0]; a2.y += (float)v2[1];                    \
                a3.x += (float)v3[0]; a3.y += (float)v3[1];                    \
                a4.x += (float)v4[0]; a4.y += (float)v4[1];                    \
                a5.x += (float)v5[0]; a5.y += (float)v5[1];                    \
                a6.x += (float)v6[0]; a6.y += (float)v6[1];                    \
                a7.x += (float)v7[0]; a7.y += (float)v7[1];                    \
                j += 8;                                                        \
            }                                                                  \
            for (; j + 1 < end; j += 2) {                                      \
                int s0 = csr_src[j];                                           \
                int s1 = csr_src[j + 1];                                       \
                f16x2 v0 = *(const f16x2*)(feat + (size_t)s0 * 128 + lane * 2);\
                f16x2 v1 = *(const f16x2*)(feat + (size_t)s1 * 128 + lane * 2);\
                a0.x += (float)v0[0]; a0.y += (float)v0[1];                    \
                a1.x += (float)v1[0]; a1.y += (float)v1[1];                    \
            }                                                                  \
            if (j < end) {                                                     \
                int s0 = csr_src[j];                                           \
                f16x2 v0 = *(const f16x2*)(feat + (size_t)s0 * 128 + lane * 2);\
                a0.x += (float)v0[0]; a0.y += (float)v0[1];                    \
            }                                                                  \
            float inv = 1.0f / fmaxf((float)(end - beg), 1.0f);                \
            f16x2 o;                                                           \
            o[0] = (_Float16)((a0.x + a1.x + a2.x + a3.x + a4.x + a5.x + a6.x + a7.x) * inv); \
            o[1] = (_Float16)((a0.y + a1.y + a2.y + a3.y + a4.y + a5.y + a6.y + a7.y) * inv); \
            uint_t off = (uint_t)(n * 256 + lane * 4) ^ (uint_t)((n & 7) << 4);\
            *(f16x2*)((char*)mlds + off) = o;                                  \
        }                                                                      \
    }

// Fused gather-mean + Conv1 (MFMA): h = relu(BN(mean@Wl.T + bl + x@Wr.T)).
__global__ __launch_bounds__(256) void k_gconv1(
    const _Float16* __restrict__ xh, const int* __restrict__ rowptr,
    const int* __restrict__ csr_src,
    const _Float16* __restrict__ w1cat, const float* __restrict__ bl,
    const float* __restrict__ bnsc, const float* __restrict__ bnsh,
    _Float16* __restrict__ hh)
{
    __shared__ _Float16 mlds[16 * 128];   // 4 KB, swizzled
    const int tid = threadIdx.x;
    const int lane = tid & 63;
    const int w = tid >> 6;               // wave = col-chunk AND gather group
    const int tile = blockIdx.x;          // 3125 * 16 nodes
    const int e = lane & 15;
    const int c = lane >> 4;
    const int node = tile * 16 + e;

    // issue weight + x-feature loads first; latency hides under the gather
    f16x8 wf[2][8];
    #pragma unroll
    for (int nt = 0; nt < 2; ++nt)
        #pragma unroll
        for (int ks = 0; ks < 8; ++ks)
            wf[nt][ks] = *(const f16x8*)(w1cat + (size_t)(w * 32 + nt * 16 + e) * 256 + ks * 32 + c * 8);
    f16x8 bfx[4];
    #pragma unroll
    for (int ks = 0; ks < 4; ++ks)
        bfx[ks] = *(const f16x8*)(xh + (size_t)node * 128 + ks * 32 + c * 8);
    f32x4 acc[2];
    #pragma unroll
    for (int nt = 0; nt < 2; ++nt)
        acc[nt] = *(const f32x4*)(bl + w * 32 + nt * 16 + c * 4);

    GATHER4_128(xh);
    __syncthreads();

    f16x8 bfm[4];
    #pragma unroll
    for (int ks = 0; ks < 4; ++ks) {
        uint_t off = (uint_t)(e * 256 + ks * 64 + c * 16) ^ (uint_t)((e & 7) << 4);
        bfm[ks] = *(const f16x8*)((const char*)mlds + off);
    }

    #pragma unroll
    for (int ks = 0; ks < 4; ++ks)
        #pragma unroll
        for (int nt = 0; nt < 2; ++nt)
            acc[nt] = __builtin_amdgcn_mfma_f32_16x16x32_f16(wf[nt][ks], bfm[ks], acc[nt], 0, 0, 0);
    #pragma unroll
    for (int ks = 0; ks < 4; ++ks)
        #pragma unroll
        for (int nt = 0; nt < 2; ++nt)
            acc[nt] = __builtin_amdgcn_mfma_f32_16x16x32_f16(wf[nt][ks + 4], bfx[ks], acc[nt], 0, 0, 0);

    #pragma unroll
    for (int nt = 0; nt < 2; ++nt) {
        int j0 = w * 32 + nt * 16 + c * 4;
        f32x4 sc = *(const f32x4*)(bnsc + j0);
        f32x4 sh = *(const f32x4*)(bnsh + j0);
        f16x4 o;
        #pragma unroll
        for (int r = 0; r < 4; ++r)
            o[r] = (_Float16)fmaxf(acc[nt][r] * sc[r] + sh[r], 0.f);
        *(f16x4*)(hh + (size_t)node * 128 + j0) = o;
    }
}

// ---------------------------------------------------------------------------
// hw = h @ c2_Wl.T (50k x 64, fp16). Transform BEFORE aggregation (linearity)
// so the conv2 gather moves 64-dim rows instead of 128-dim: bytes halved.
__global__ __launch_bounds__(256) void k_hw(
    const _Float16* __restrict__ hh, const _Float16* __restrict__ w2cat,
    _Float16* __restrict__ hw)
{
    const int tid = threadIdx.x;
    const int lane = tid & 63;
    const int e = lane & 15;
    const int c = lane >> 4;
    const int w = tid >> 6;               // 4 waves = 4 col-chunks of 16
    const int node = blockIdx.x * 16 + e;

    f16x8 wf[4];
    #pragma unroll
    for (int ks = 0; ks < 4; ++ks)
        wf[ks] = *(const f16x8*)(w2cat + (size_t)(w * 16 + e) * 256 + ks * 32 + c * 8);  // Wl half
    f16x8 bf[4];
    #pragma unroll
    for (int ks = 0; ks < 4; ++ks)
        bf[ks] = *(const f16x8*)(hh + (size_t)node * 128 + ks * 32 + c * 8);

    f32x4 acc = {0.f, 0.f, 0.f, 0.f};
    #pragma unroll
    for (int ks = 0; ks < 4; ++ks)
        acc = __builtin_amdgcn_mfma_f32_16x16x32_f16(wf[ks], bf[ks], acc, 0, 0, 0);

    f16x4 o;
    #pragma unroll
    for (int r = 0; r < 4; ++r) o[r] = (_Float16)acc[r];
    *(f16x4*)(hw + (size_t)node * 64 + w * 16 + c * 4) = o;
}

// ---------------------------------------------------------------------------
// Fused 64-dim gather-mean + Conv2 root side:
// z = mean(hw[src]) + bl + h@Wr.T  -> bf16. 16 loads in flight in main loop.
__global__ __launch_bounds__(256) void k_gconv2(
    const _Float16* __restrict__ hh, const _Float16* __restrict__ hw,
    const int* __restrict__ rowptr, const int* __restrict__ csr_src,
    const _Float16* __restrict__ w2cat, const float* __restrict__ bl,
    ushort_t* __restrict__ zbf)
{
    __shared__ float mlds32[16 * 64];     // 4 KB f32, swizzled
    const int tid = threadIdx.x;
    const int lane = tid & 63;
    const int w = tid >> 6;
    const int tile = blockIdx.x;
    const int e = lane & 15;
    const int c = lane >> 4;
    const int node = tile * 16 + e;

    // weight (root half) + h-feature loads issued before the gather
    f16x8 wf[4];
    #pragma unroll
    for (int ks = 0; ks < 4; ++ks)
        wf[ks] = *(const f16x8*)(w2cat + (size_t)(w * 16 + e) * 256 + 128 + ks * 32 + c * 8);
    f16x8 bfx[4];
    #pragma unroll
    for (int ks = 0; ks < 4; ++ks)
        bfx[ks] = *(const f16x8*)(hh + (size_t)node * 128 + ks * 32 + c * 8);

    // 64-dim gather: lane = dim, one fp16 per lane per row (128B row/wave).
    #pragma unroll 1
    for (int q = 0; q < 4; ++q) {
        int n = w * 4 + q;
        int node4 = tile * 16 + n;
        int beg = __builtin_amdgcn_readfirstlane(rowptr[node4]);
        int end = __builtin_amdgcn_readfirstlane(rowptr[node4 + 1]);
        float a0 = 0.f, a1 = 0.f, a2 = 0.f, a3 = 0.f;
        float a4 = 0.f, a5 = 0.f, a6 = 0.f, a7 = 0.f;
        int j = beg;
        for (; j + 15 < end; j += 16) {
            int s0 = csr_src[j];      int s1 = csr_src[j + 1];
            int s2 = csr_src[j + 2];  int s3 = csr_src[j + 3];
            int s4 = csr_src[j + 4];  int s5 = csr_src[j + 5];
            int s6 = csr_src[j + 6];  int s7 = csr_src[j + 7];
            int s8 = csr_src[j + 8];  int s9 = csr_src[j + 9];
            int sa = csr_src[j + 10]; int sb = csr_src[j + 11];
            int sc = csr_src[j + 12]; int sd = csr_src[j + 13];
            int se = csr_src[j + 14]; int sf = csr_src[j + 15];
            float v0 = (float)hw[(size_t)s0 * 64 + lane];
            float v1 = (float)hw[(size_t)s1 * 64 + lane];
            float v2 = (float)hw[(size_t)s2 * 64 + lane];
            float v3 = (float)hw[(size_t)s3 * 64 + lane];
            float v4 = (float)hw[(size_t)s4 * 64 + lane];
            float v5 = (float)hw[(size_t)s5 * 64 + lane];
            float v6 = (float)hw[(size_t)s6 * 64 + lane];
            float v7 = (float)hw[(size_t)s7 * 64 + lane];
            float v8 = (float)hw[(size_t)s8 * 64 + lane];
            float v9 = (float)hw[(size_t)s9 * 64 + lane];
            float va = (float)hw[(size_t)sa * 64 + lane];
            float vb = (float)hw[(size_t)sb * 64 + lane];
            float vc = (float)hw[(size_t)sc * 64 + lane];
            float vd = (float)hw[(size_t)sd * 64 + lane];
            float ve = (float)hw[(size_t)se * 64 + lane];
            float vf = (float)hw[(size_t)sf * 64 + lane];
            a0 += v0 + v8; a1 += v1 + v9; a2 += v2 + va; a3 += v3 + vb;
            a4 += v4 + vc; a5 += v5 + vd; a6 += v6 + ve; a7 += v7 + vf;
        }
        if (j + 7 < end) {
            int s0 = csr_src[j];     int s1 = csr_src[j + 1];
            int s2 = csr_src[j + 2]; int s3 = csr_src[j + 3];
            int s4 = csr_src[j + 4]; int s5 = csr_src[j + 5];
            int s6 = csr_src[j + 6]; int s7 = csr_src[j + 7];
            a0 += (float)hw[(size_t)s0 * 64 + lane];
            a1 += (float)hw[(size_t)s1 * 64 + lane];
            a2 += (float)hw[(size_t)s2 * 64 + lane];
            a3 += (float)hw[(size_t)s3 * 64 + lane];
            a4 += (float)hw[(size_t)s4 * 64 + lane];
            a5 += (float)hw[(size_t)s5 * 64 + lane];
            a6 += (float)hw[(size_t)s6 * 64 + lane];
            a7 += (float)hw[(size_t)s7 * 64 + lane];
            j += 8;
        }
        for (; j + 1 < end; j += 2) {
            int s0 = csr_src[j];
            int s1 = csr_src[j + 1];
            a0 += (float)hw[(size_t)s0 * 64 + lane];
            a1 += (float)hw[(size_t)s1 * 64 + lane];
        }
        if (j < end) {
            int s0 = csr_src[j];
            a0 += (float)hw[(size_t)s0 * 64 + lane];
        }
        float inv = 1.0f / fmaxf((float)(end - beg), 1.0f);
        float m = (a0 + a1 + a2 + a3 + a4 + a5 + a6 + a7) * inv;
        uint_t off = (uint_t)(n * 256 + lane * 4) ^ (uint_t)((n & 7) << 4);
        *(float*)((char*)mlds32 + off) = m;
    }
    __syncthreads();

    // acc = bias + gathered mean (already Wl-transformed) + h@Wr.T
    f32x4 acc = *(const f32x4*)(bl + w * 16 + c * 4);
    {
        uint_t off = (uint_t)(e * 256 + (w * 16 + c * 4) * 4) ^ (uint_t)((e & 7) << 4);
        f32x4 mv = *(const f32x4*)((const char*)mlds32 + off);
        acc[0] += mv[0]; acc[1] += mv[1]; acc[2] += mv[2]; acc[3] += mv[3];
    }

    #pragma unroll
    for (int ks = 0; ks < 4; ++ks)
        acc = __builtin_amdgcn_mfma_f32_16x16x32_f16(wf[ks], bfx[ks], acc, 0, 0, 0);

    int j0 = w * 16 + c * 4;
    uint2 pk;
    pk.x = pk2bf(acc[0], acc[1]);
    pk.y = pk2bf(acc[2], acc[3]);
    *(uint2*)(zbf + (size_t)node * 64 + j0) = pk;
}

// ---------------------------------------------------------------------------
// Edge head via MFMA: grid-stride with DEPTH-3 z/ep prefetch (zA/zB/zC static
// rotation; compute ~350cyc/tile now covers ~2 tiles of L3-miss latency).
__global__ __launch_bounds__(256) void k_edge(
    const ushort_t* __restrict__ zbf, const int* __restrict__ ep,
    const ushort_t* __restrict__ w1bf, const float* __restrict__ b1,
    const ushort_t* __restrict__ w2bf, const float* __restrict__ b2,
    const float* __restrict__ W3, const float* __restrict__ b3,
    float* __restrict__ out)
{
    __shared__ ushort_t a1lds[4][16 * 64];
    const int tid  = threadIdx.x;
    const int lane = tid & 63;
    const int e    = lane & 15;
    const int c    = lane >> 4;
    ushort_t* lds  = &a1lds[tid >> 6][0];
    const uint_t swz = (uint_t)((e & 7) << 4);

    bf16x8 w1f[4][4];
    #pragma unroll
    for (int mt = 0; mt < 4; ++mt)
        #pragma unroll
        for (int ks = 0; ks < 4; ++ks)
            w1f[mt][ks] = *(const bf16x8*)(w1bf + (mt * 16 + e) * 128 + ks * 32 + c * 8);

    bf16x8 w2f[2][2];
    #pragma unroll
    for (int mt2 = 0; mt2 < 2; ++mt2)
        #pragma unroll
        for (int ks2 = 0; ks2 < 2; ++ks2)
            w2f[mt2][ks2] = *(const bf16x8*)(w2bf + (mt2 * 16 + e) * 64 + ks2 * 32 + c * 8);

    f32x4 bias1[4];
    #pragma unroll
    for (int mt = 0; mt < 4; ++mt) bias1[mt] = *(const f32x4*)(b1 + mt * 16 + c * 4);
    f32x4 bias2[2];
    #pragma unroll
    for (int mt2 = 0; mt2 < 2; ++mt2) bias2[mt2] = *(const f32x4*)(b2 + mt2 * 16 + c * 4);
    f32x4 w3v[2];
    #pragma unroll
    for (int mt2 = 0; mt2 < 2; ++mt2) w3v[mt2] = *(const f32x4*)(W3 + mt2 * 16 + c * 4);
    const float b3v = b3[0];

    const int nw = (gridDim.x * blockDim.x) >> 6;
    const int NT = NE / 16;

#define LOADZ(T, dst)                                                         \
    {                                                                         \
        int p = (T) * 16 + e;                                                 \
        int ni = ep[p];                                                       \
        int nj = ep[NE + p];                                                  \
        const ushort_t* zi = zbf + (size_t)ni * DOUT;                         \
        const ushort_t* zj = zbf + (size_t)nj * DOUT;                         \
        dst[0] = *(const bf16x8*)(zi + c * 8);                                \
        dst[1] = *(const bf16x8*)(zi + 32 + c * 8);                           \
        dst[2] = *(const bf16x8*)(zj + c * 8);                                \
        dst[3] = *(const bf16x8*)(zj + 32 + c * 8);                           \
    }

#define COMPUTE(T, bfr)                                                       \
    {                                                                         \
        f32x4 acc[4];                                                         \
        _Pragma("unroll")                                                     \
        for (int mt = 0; mt < 4; ++mt) acc[mt] = bias1[mt];                   \
        _Pragma("unroll")                                                     \
        for (int ks = 0; ks < 4; ++ks)                                        \
            _Pragma("unroll")                                                 \
            for (int mt = 0; mt < 4; ++mt)                                    \
                acc[mt] = __builtin_amdgcn_mfma_f32_16x16x32_bf16(            \
                    w1f[mt][ks], bfr[ks], acc[mt], 0, 0, 0);                  \
        _Pragma("unroll")                                                     \
        for (int mt = 0; mt < 4; ++mt) {                                      \
            uint_t lo = pk2bf(fmaxf(acc[mt][0], 0.f), fmaxf(acc[mt][1], 0.f));\
            uint_t hi = pk2bf(fmaxf(acc[mt][2], 0.f), fmaxf(acc[mt][3], 0.f));\
            uint_t off = (uint_t)(e * 128 + mt * 32 + c * 8) ^ swz;           \
            *(uint2*)((char*)lds + off) = make_uint2(lo, hi);                 \
        }                                                                     \
        bf16x8 b2f[2];                                                        \
        _Pragma("unroll")                                                     \
        for (int ks2 = 0; ks2 < 2; ++ks2) {                                   \
            uint_t off = (uint_t)(e * 128 + ks2 * 64 + c * 16) ^ swz;         \
            b2f[ks2] = *(const bf16x8*)((const char*)lds + off);              \
        }                                                                     \
        f32x4 a2[2];                                                          \
        _Pragma("unroll")                                                     \
        for (int mt2 = 0; mt2 < 2; ++mt2) a2[mt2] = bias2[mt2];               \
        _Pragma("unroll")                                                     \
        for (int ks2 = 0; ks2 < 2; ++ks2)                                     \
            _Pragma("unroll")                                                 \
            for (int mt2 = 0; mt2 < 2; ++mt2)                                 \
                a2[mt2] = __builtin_amdgcn_mfma_f32_16x16x32_bf16(            \
                    w2f[mt2][ks2], b2f[ks2], a2[mt2], 0, 0, 0);               \
        float t3 = b3v;                                                       \
        _Pragma("unroll")                                                     \
        for (int mt2 = 0; mt2 < 2; ++mt2)                                     \
            _Pragma("unroll")                                                 \
            for (int r = 0; r < 4; ++r)                                       \
                t3 += fmaxf(a2[mt2][r], 0.f) * w3v[mt2][r];                   \
        t3 += __shfl_xor(t3, 16);                                             \
        t3 += __shfl_xor(t3, 32);                                             \
        if (lane < 16) {                                                      \
            float ex = __expf(-t3);                                           \
            out[(T) * 16 + lane] = __builtin_amdgcn_rcpf(1.f + ex);           \
        }                                                                     \
    }

    bf16x8 zA[4], zB[4], zC[4];
    int ta = (blockIdx.x * blockDim.x + tid) >> 6;    // wave id
    if (ta >= NT) return;
    int tb = ta + nw;
    int tc = tb + nw;
    LOADZ(ta, zA);
    if (tb < NT) LOADZ(tb, zB);
    if (tc < NT) LOADZ(tc, zC);
    while (true) {
        COMPUTE(ta, zA);
        ta += 3 * nw;
        if (ta < NT) LOADZ(ta, zA);
        if (tb >= NT) break;
        COMPUTE(tb, zB);
        tb += 3 * nw;
        if (tb < NT) LOADZ(tb, zB);
        if (tc >= NT) break;
        COMPUTE(tc, zC);
        tc += 3 * nw;
        if (tc < NT) LOADZ(tc, zC);
        if (ta >= NT) break;
    }

#undef LOADZ
#undef COMPUTE
}

// ---------------------------------------------------------------------------
extern "C" void kernel_launch(void* const* d_in, const int* in_sizes, int n_in,
                              void* d_out, int out_size, void* d_ws, size_t ws_size,
                              hipStream_t stream)
{
    const float* x     = (const float*)d_in[0];
    const int*   ei    = (const int*)d_in[1];
    const int*   ep    = (const int*)d_in[2];
    const float* c1_Wl = (const float*)d_in[3];
    const float* c1_bl = (const float*)d_in[4];
    const float* c1_Wr = (const float*)d_in[5];
    const float* bn_g  = (const float*)d_in[6];
    const float* bn_b  = (const float*)d_in[7];
    const float* bn_m  = (const float*)d_in[8];
    const float* bn_v  = (const float*)d_in[9];
    const float* c2_Wl = (const float*)d_in[10];
    const float* c2_bl = (const float*)d_in[11];
    const float* c2_Wr = (const float*)d_in[12];
    const float* e_W1  = (const float*)d_in[13];
    const float* e_b1  = (const float*)d_in[14];
    const float* e_W2  = (const float*)d_in[15];
    const float* e_b2  = (const float*)d_in[16];
    const float* e_W3  = (const float*)d_in[17];
    const float* e_b3  = (const float*)d_in[18];
    float* out = (float*)d_out;

    _Float16* xh    = (_Float16*)d_ws;
    _Float16* hwbuf = xh + (size_t)NN * DIN;
    _Float16* hh    = hwbuf + (size_t)NN * DIN;
    ushort_t* zbf   = (ushort_t*)(hh + (size_t)NN * DHID);
    _Float16* w1cat = (_Float16*)(zbf + (size_t)NN * DOUT);
    _Float16* w2cat = w1cat + 128 * 256;
    ushort_t* w1bf  = (ushort_t*)(w2cat + 64 * 256);
    ushort_t* w2bf  = w1bf + 64 * 128;
    float*    bnsc  = (float*)(w2bf + 32 * 64);
    float*    bnsh  = bnsc + 128;
    int*      deg     = (int*)(bnsh + 128);
    int*      cursor  = deg + 50048;
    int*      rowptr  = cursor + 50048;
    int*      csr_src = rowptr + 50052;
    int*      part    = csr_src + 800000;

    hipMemsetAsync(deg, 0, (size_t)(50048 * 2) * sizeof(int), stream);

    k_deg_xcast<<<6250, 256, 0, stream>>>(ei, deg, x, xh);
    k_scan1_prep<<<50, 256, 0, stream>>>(deg, part,
                                         c1_Wl, c1_Wr, c2_Wl, c2_Wr,
                                         bn_g, bn_b, bn_m, bn_v, e_W1, e_W2,
                                         w1cat, w2cat, w1bf, w2bf, bnsc, bnsh);
    k_scan3<<<49, 256, 0, stream>>>(deg, part, rowptr);
    k_fill <<<3125, 256, 0, stream>>>(ei, rowptr, cursor, csr_src);

    k_gconv1<<<3125, 256, 0, stream>>>(xh, rowptr, csr_src, w1cat, c1_bl, bnsc, bnsh, hh);
    k_hw    <<<3125, 256, 0, stream>>>(hh, w2cat, hwbuf);
    k_gconv2<<<3125, 256, 0, stream>>>(hh, hwbuf, rowptr, csr_src, w2cat, c2_bl, zbf);

    k_edge<<<1024, 256, 0, stream>>>(zbf, ep, w1bf, e_b1, w2bf, e_b2,
                                     e_W3, e_b3, out);
}

// Round 16
// 280.590 us; speedup vs baseline: 1.0190x; 1.0190x over previous
//
#include <hip/hip_runtime.h>
#include <hip/hip_bf16.h>
#include <math.h>

#define NN 50000
#define NE 800000
#define DIN 128
#define DHID 128
#define DOUT 64
#define BN_EPS 1e-5f

typedef __attribute__((ext_vector_type(8))) short bf16x8;
typedef __attribute__((ext_vector_type(8))) _Float16 f16x8;
typedef __attribute__((ext_vector_type(4))) _Float16 f16x4;
typedef __attribute__((ext_vector_type(2))) _Float16 f16x2;
typedef __attribute__((ext_vector_type(4))) float f32x4;
typedef unsigned short ushort_t;
typedef unsigned int uint_t;

__device__ __forceinline__ ushort_t f2bf(float f) {
    uint_t u = __float_as_uint(f);
    uint_t r = (u + 0x7FFFu + ((u >> 16) & 1u)) >> 16;   // RNE
    return (ushort_t)r;
}

__device__ __forceinline__ uint_t pk2bf(float a, float b) {
    __hip_bfloat16 x = __float2bfloat16(a);
    __hip_bfloat16 y = __float2bfloat16(b);
    ushort_t ux = *reinterpret_cast<ushort_t*>(&x);
    ushort_t uy = *reinterpret_cast<ushort_t*>(&y);
    return (uint_t)ux | ((uint_t)uy << 16);
}

// ---------------------------------------------------------------------------
// Fused: blocks [0,3125) histogram dst degrees; blocks [3125,6250) cast x->fp16.
__global__ __launch_bounds__(256) void k_deg_xcast(
    const int* __restrict__ ei, int* __restrict__ deg,
    const float* __restrict__ x, _Float16* __restrict__ xh)
{
    int b = blockIdx.x;
    if (b < 3125) {
        int e = b * 256 + threadIdx.x;
        atomicAdd(deg + ei[NE + e], 1);
    } else {
        int i = (b - 3125) * 256 + threadIdx.x;
        const float4* src = (const float4*)x + (size_t)i * 2;
        float4 a = src[0], c = src[1];
        f16x8 o;
        o[0] = (_Float16)a.x; o[1] = (_Float16)a.y; o[2] = (_Float16)a.z; o[3] = (_Float16)a.w;
        o[4] = (_Float16)c.x; o[5] = (_Float16)c.y; o[6] = (_Float16)c.z; o[7] = (_Float16)c.w;
        *(f16x8*)(xh + (size_t)i * 8) = o;
    }
}

// ---------------------------------------------------------------------------
// Scan stage 1 (blocks 0..48) + weight prep (block 49).
__global__ __launch_bounds__(256) void k_scan1_prep(
    const int* __restrict__ deg, int* __restrict__ part,
    const float* __restrict__ c1_Wl, const float* __restrict__ c1_Wr,
    const float* __restrict__ c2_Wl, const float* __restrict__ c2_Wr,
    const float* __restrict__ gam, const float* __restrict__ bet,
    const float* __restrict__ bmean, const float* __restrict__ bvar,
    const float* __restrict__ eW1, const float* __restrict__ eW2,
    _Float16* __restrict__ w1cat, _Float16* __restrict__ w2cat,
    ushort_t* __restrict__ w1bf, ushort_t* __restrict__ w2bf,
    float* __restrict__ bnsc, float* __restrict__ bnsh)
{
    int t = threadIdx.x;
    if (blockIdx.x < 49) {
        __shared__ int s[256];
        int g = blockIdx.x * 256 + t;
        int v = 0;
        if (g < 12500) { int4 d = ((const int4*)deg)[g]; v = d.x + d.y + d.z + d.w; }
        s[t] = v;
        __syncthreads();
        #pragma unroll
        for (int off = 128; off > 0; off >>= 1) {
            if (t < off) s[t] += s[t + off];
            __syncthreads();
        }
        if (t == 0) part[blockIdx.x] = s[0];
    } else {
        for (int i = t; i < 128 * 128; i += 256) {
            int row = i >> 7, k = i & 127;
            w1cat[row * 256 + k]       = (_Float16)c1_Wl[i];
            w1cat[row * 256 + 128 + k] = (_Float16)c1_Wr[i];
        }
        for (int i = t; i < 64 * 128; i += 256) {
            int row = i >> 7, k = i & 127;
            w2cat[row * 256 + k]       = (_Float16)c2_Wl[i];
            w2cat[row * 256 + 128 + k] = (_Float16)c2_Wr[i];
        }
        for (int i = t; i < 64 * 128; i += 256) w1bf[i] = f2bf(eW1[i]);
        for (int i = t; i < 32 * 64; i += 256)  w2bf[i] = f2bf(eW2[i]);
        for (int i = t; i < 128; i += 256) {
            float s = gam[i] * rsqrtf(bvar[i] + BN_EPS);
            bnsc[i] = s;
            bnsh[i] = bet[i] - bmean[i] * s;
        }
    }
}

// Scan stage 2: per-block exclusive scan + block offset.
__global__ __launch_bounds__(256) void k_scan3(
    const int* __restrict__ deg, const int* __restrict__ part, int* __restrict__ rowptr)
{
    __shared__ int s[256];
    __shared__ int p[64];
    int t = threadIdx.x;
    int b = blockIdx.x;
    int g = b * 256 + t;
    int4 d = make_int4(0, 0, 0, 0);
    if (g < 12500) d = ((const int4*)deg)[g];
    int sum4 = d.x + d.y + d.z + d.w;
    s[t] = sum4;
    if (t < 49) p[t] = part[t];
    __syncthreads();
    #pragma unroll
    for (int off = 1; off < 256; off <<= 1) {
        int v = (t >= off) ? s[t - off] : 0;
        __syncthreads();
        s[t] += v;
        __syncthreads();
    }
    int blockoff = 0;
    for (int i = 0; i < b; ++i) blockoff += p[i];
    int off0 = blockoff + s[t] - sum4;
    if (g < 12500) {
        int4 o;
        o.x = off0;
        o.y = off0 + d.x;
        o.z = o.y + d.y;
        o.w = o.z + d.z;
        ((int4*)rowptr)[g] = o;
        if (g == 12499) rowptr[NN] = o.w + d.w;
    }
}

// Fill CSR column (src) array.
__global__ __launch_bounds__(256) void k_fill(
    const int* __restrict__ ei, const int* __restrict__ rowptr,
    int* __restrict__ cursor, int* __restrict__ csr_src)
{
    int e = blockIdx.x * blockDim.x + threadIdx.x;
    if (e >= NE) return;
    int dst = ei[NE + e];
    int slot = atomicAdd(cursor + dst, 1);
    csr_src[rowptr[dst] + slot] = ei[e];
}

// ---------------------------------------------------------------------------
// 128-dim gather (proven 8-deep form, 68 µs): wave gathers 4 nodes' means
// into a swizzled fp16 LDS tile. f16x2/lane (full 256B row per instruction).
#define GATHER4_128(feat)                                                      \
    {                                                                          \
        _Pragma("unroll 1")                                                    \
        for (int q = 0; q < 4; ++q) {                                          \
            int n = w * 4 + q;                                                 \
            int node4 = tile * 16 + n;                                         \
            int beg = __builtin_amdgcn_readfirstlane(rowptr[node4]);           \
            int end = __builtin_amdgcn_readfirstlane(rowptr[node4 + 1]);       \
            float2 a0 = {0.f,0.f}, a1 = {0.f,0.f}, a2 = {0.f,0.f}, a3 = {0.f,0.f}; \
            float2 a4 = {0.f,0.f}, a5 = {0.f,0.f}, a6 = {0.f,0.f}, a7 = {0.f,0.f}; \
            int j = beg;                                                       \
            for (; j + 7 < end; j += 8) {                                      \
                int s0 = csr_src[j];     int s1 = csr_src[j + 1];              \
                int s2 = csr_src[j + 2]; int s3 = csr_src[j + 3];              \
                int s4 = csr_src[j + 4]; int s5 = csr_src[j + 5];              \
                int s6 = csr_src[j + 6]; int s7 = csr_src[j + 7];              \
                f16x2 v0 = *(const f16x2*)(feat + (size_t)s0 * 128 + lane * 2);\
                f16x2 v1 = *(const f16x2*)(feat + (size_t)s1 * 128 + lane * 2);\
                f16x2 v2 = *(const f16x2*)(feat + (size_t)s2 * 128 + lane * 2);\
                f16x2 v3 = *(const f16x2*)(feat + (size_t)s3 * 128 + lane * 2);\
                f16x2 v4 = *(const f16x2*)(feat + (size_t)s4 * 128 + lane * 2);\
                f16x2 v5 = *(const f16x2*)(feat + (size_t)s5 * 128 + lane * 2);\
                f16x2 v6 = *(const f16x2*)(feat + (size_t)s6 * 128 + lane * 2);\
                f16x2 v7 = *(const f16x2*)(feat + (size_t)s7 * 128 + lane * 2);\
                a0.x += (float)v0[0]; a0.y += (float)v0[1];                    \
                a1.x += (float)v1[0]; a1.y += (float)v1[1];                    \
                a2.x += (float)v2[0]; a2.y += (float)v2[1];                    \
                a3.x += (float)v3[0]; a3.y += (float)v3[1];                    \
                a4.x += (float)v4[0]; a4.y += (float)v4[1];                    \
                a5.x += (float)v5[0]; a5.y += (float)v5[1];                    \
                a6.x += (float)v6[0]; a6.y += (float)v6[1];                    \
                a7.x += (float)v7[0]; a7.y += (float)v7[1];                    \
            }                                                                  \
            for (; j + 1 < end; j += 2) {                                      \
                int s0 = csr_src[j];                                           \
                int s1 = csr_src[j + 1];                                       \
                f16x2 v0 = *(const f16x2*)(feat + (size_t)s0 * 128 + lane * 2);\
                f16x2 v1 = *(const f16x2*)(feat + (size_t)s1 * 128 + lane * 2);\
                a0.x += (float)v0[0]; a0.y += (float)v0[1];                    \
                a1.x += (float)v1[0]; a1.y += (float)v1[1];                    \
            }                                                                  \
            if (j < end) {                                                     \
                int s0 = csr_src[j];                                           \
                f16x2 v0 = *(const f16x2*)(feat + (size_t)s0 * 128 + lane * 2);\
                a0.x += (float)v0[0]; a0.y += (float)v0[1];                    \
            }                                                                  \
            float inv = 1.0f / fmaxf((float)(end - beg), 1.0f);                \
            f16x2 o;                                                           \
            o[0] = (_Float16)((a0.x + a1.x + a2.x + a3.x + a4.x + a5.x + a6.x + a7.x) * inv); \
            o[1] = (_Float16)((a0.y + a1.y + a2.y + a3.y + a4.y + a5.y + a6.y + a7.y) * inv); \
            uint_t off = (uint_t)(n * 256 + lane * 4) ^ (uint_t)((n & 7) << 4);\
            *(f16x2*)((char*)mlds + off) = o;                                  \
        }                                                                      \
    }

// ---------------------------------------------------------------------------
// Fused gather-mean + Conv1 + hw epilogue:
//   h  = relu(BN(mean@Wl1.T + bl1 + x@Wr1.T))        -> hh (global, fp16)
//   hw = h @ c2_Wl.T                                  -> hw (global, fp16)
// h is staged in a second swizzled LDS tile so the block can compute hw
// without re-reading hh from global (replaces the separate k_hw kernel).
__global__ __launch_bounds__(256) void k_gconv1(
    const _Float16* __restrict__ xh, const int* __restrict__ rowptr,
    const int* __restrict__ csr_src,
    const _Float16* __restrict__ w1cat, const float* __restrict__ bl,
    const float* __restrict__ bnsc, const float* __restrict__ bnsh,
    const _Float16* __restrict__ w2cat, _Float16* __restrict__ hh,
    _Float16* __restrict__ hw)
{
    __shared__ _Float16 mlds[16 * 128];   // mean tile, 4 KB, swizzled
    __shared__ _Float16 hlds[16 * 128];   // h tile, 4 KB, swizzled
    const int tid = threadIdx.x;
    const int lane = tid & 63;
    const int w = tid >> 6;               // wave = col-chunk AND gather group
    const int tile = blockIdx.x;          // 3125 * 16 nodes
    const int e = lane & 15;
    const int c = lane >> 4;
    const int node = tile * 16 + e;

    // issue weight + x-feature loads first; latency hides under the gather
    f16x8 wf[2][8];
    #pragma unroll
    for (int nt = 0; nt < 2; ++nt)
        #pragma unroll
        for (int ks = 0; ks < 8; ++ks)
            wf[nt][ks] = *(const f16x8*)(w1cat + (size_t)(w * 32 + nt * 16 + e) * 256 + ks * 32 + c * 8);
    f16x8 bfx[4];
    #pragma unroll
    for (int ks = 0; ks < 4; ++ks)
        bfx[ks] = *(const f16x8*)(xh + (size_t)node * 128 + ks * 32 + c * 8);
    f32x4 acc[2];
    #pragma unroll
    for (int nt = 0; nt < 2; ++nt)
        acc[nt] = *(const f32x4*)(bl + w * 32 + nt * 16 + c * 4);

    GATHER4_128(xh);
    __syncthreads();

    f16x8 bfm[4];
    #pragma unroll
    for (int ks = 0; ks < 4; ++ks) {
        uint_t off = (uint_t)(e * 256 + ks * 64 + c * 16) ^ (uint_t)((e & 7) << 4);
        bfm[ks] = *(const f16x8*)((const char*)mlds + off);
    }

    #pragma unroll
    for (int ks = 0; ks < 4; ++ks)
        #pragma unroll
        for (int nt = 0; nt < 2; ++nt)
            acc[nt] = __builtin_amdgcn_mfma_f32_16x16x32_f16(wf[nt][ks], bfm[ks], acc[nt], 0, 0, 0);
    #pragma unroll
    for (int ks = 0; ks < 4; ++ks)
        #pragma unroll
        for (int nt = 0; nt < 2; ++nt)
            acc[nt] = __builtin_amdgcn_mfma_f32_16x16x32_f16(wf[nt][ks + 4], bfx[ks], acc[nt], 0, 0, 0);

    #pragma unroll
    for (int nt = 0; nt < 2; ++nt) {
        int j0 = w * 32 + nt * 16 + c * 4;
        f32x4 sc = *(const f32x4*)(bnsc + j0);
        f32x4 sh = *(const f32x4*)(bnsh + j0);
        f16x4 o;
        #pragma unroll
        for (int r = 0; r < 4; ++r)
            o[r] = (_Float16)fmaxf(acc[nt][r] * sc[r] + sh[r], 0.f);
        *(f16x4*)(hh + (size_t)node * 128 + j0) = o;
        // stage into h-LDS tile (row = node e within tile, swizzled)
        uint_t hoff = (uint_t)(e * 256 + j0 * 2) ^ (uint_t)((e & 7) << 4);
        *(f16x4*)((char*)hlds + hoff) = o;
    }

    // hw epilogue: hw[node] = h[node] @ c2_Wl.T (weights hot in L2)
    f16x8 wf2[4];
    #pragma unroll
    for (int ks = 0; ks < 4; ++ks)
        wf2[ks] = *(const f16x8*)(w2cat + (size_t)(w * 16 + e) * 256 + ks * 32 + c * 8);
    __syncthreads();

    f16x8 bfh[4];
    #pragma unroll
    for (int ks = 0; ks < 4; ++ks) {
        uint_t off = (uint_t)(e * 256 + ks * 64 + c * 16) ^ (uint_t)((e & 7) << 4);
        bfh[ks] = *(const f16x8*)((const char*)hlds + off);
    }
    f32x4 acc2 = {0.f, 0.f, 0.f, 0.f};
    #pragma unroll
    for (int ks = 0; ks < 4; ++ks)
        acc2 = __builtin_amdgcn_mfma_f32_16x16x32_f16(wf2[ks], bfh[ks], acc2, 0, 0, 0);

    f16x4 ohw;
    #pragma unroll
    for (int r = 0; r < 4; ++r) ohw[r] = (_Float16)acc2[r];
    *(f16x4*)(hw + (size_t)node * 64 + w * 16 + c * 4) = ohw;
}

// ---------------------------------------------------------------------------
// Fused 64-dim gather-mean + Conv2 root side:
// z = mean(hw[src]) + bl + h@Wr.T  -> bf16. 8-deep gather (proven form).
__global__ __launch_bounds__(256) void k_gconv2(
    const _Float16* __restrict__ hh, const _Float16* __restrict__ hw,
    const int* __restrict__ rowptr, const int* __restrict__ csr_src,
    const _Float16* __restrict__ w2cat, const float* __restrict__ bl,
    ushort_t* __restrict__ zbf)
{
    __shared__ float mlds32[16 * 64];     // 4 KB f32, swizzled
    const int tid = threadIdx.x;
    const int lane = tid & 63;
    const int w = tid >> 6;
    const int tile = blockIdx.x;
    const int e = lane & 15;
    const int c = lane >> 4;
    const int node = tile * 16 + e;

    // weight (root half) + h-feature loads issued before the gather
    f16x8 wf[4];
    #pragma unroll
    for (int ks = 0; ks < 4; ++ks)
        wf[ks] = *(const f16x8*)(w2cat + (size_t)(w * 16 + e) * 256 + 128 + ks * 32 + c * 8);
    f16x8 bfx[4];
    #pragma unroll
    for (int ks = 0; ks < 4; ++ks)
        bfx[ks] = *(const f16x8*)(hh + (size_t)node * 128 + ks * 32 + c * 8);

    // 64-dim gather: lane = dim, one fp16 per lane per row (128B row/wave).
    #pragma unroll 1
    for (int q = 0; q < 4; ++q) {
        int n = w * 4 + q;
        int node4 = tile * 16 + n;
        int beg = __builtin_amdgcn_readfirstlane(rowptr[node4]);
        int end = __builtin_amdgcn_readfirstlane(rowptr[node4 + 1]);
        float a0 = 0.f, a1 = 0.f, a2 = 0.f, a3 = 0.f;
        float a4 = 0.f, a5 = 0.f, a6 = 0.f, a7 = 0.f;
        int j = beg;
        for (; j + 7 < end; j += 8) {
            int s0 = csr_src[j];     int s1 = csr_src[j + 1];
            int s2 = csr_src[j + 2]; int s3 = csr_src[j + 3];
            int s4 = csr_src[j + 4]; int s5 = csr_src[j + 5];
            int s6 = csr_src[j + 6]; int s7 = csr_src[j + 7];
            a0 += (float)hw[(size_t)s0 * 64 + lane];
            a1 += (float)hw[(size_t)s1 * 64 + lane];
            a2 += (float)hw[(size_t)s2 * 64 + lane];
            a3 += (float)hw[(size_t)s3 * 64 + lane];
            a4 += (float)hw[(size_t)s4 * 64 + lane];
            a5 += (float)hw[(size_t)s5 * 64 + lane];
            a6 += (float)hw[(size_t)s6 * 64 + lane];
            a7 += (float)hw[(size_t)s7 * 64 + lane];
        }
        for (; j + 1 < end; j += 2) {
            int s0 = csr_src[j];
            int s1 = csr_src[j + 1];
            a0 += (float)hw[(size_t)s0 * 64 + lane];
            a1 += (float)hw[(size_t)s1 * 64 + lane];
        }
        if (j < end) {
            int s0 = csr_src[j];
            a0 += (float)hw[(size_t)s0 * 64 + lane];
        }
        float inv = 1.0f / fmaxf((float)(end - beg), 1.0f);
        float m = (a0 + a1 + a2 + a3 + a4 + a5 + a6 + a7) * inv;
        uint_t off = (uint_t)(n * 256 + lane * 4) ^ (uint_t)((n & 7) << 4);
        *(float*)((char*)mlds32 + off) = m;
    }
    __syncthreads();

    // acc = bias + gathered mean (already Wl-transformed) + h@Wr.T
    f32x4 acc = *(const f32x4*)(bl + w * 16 + c * 4);
    {
        uint_t off = (uint_t)(e * 256 + (w * 16 + c * 4) * 4) ^ (uint_t)((e & 7) << 4);
        f32x4 mv = *(const f32x4*)((const char*)mlds32 + off);
        acc[0] += mv[0]; acc[1] += mv[1]; acc[2] += mv[2]; acc[3] += mv[3];
    }

    #pragma unroll
    for (int ks = 0; ks < 4; ++ks)
        acc = __builtin_amdgcn_mfma_f32_16x16x32_f16(wf[ks], bfx[ks], acc, 0, 0, 0);

    int j0 = w * 16 + c * 4;
    uint2 pk;
    pk.x = pk2bf(acc[0], acc[1]);
    pk.y = pk2bf(acc[2], acc[3]);
    *(uint2*)(zbf + (size_t)node * 64 + j0) = pk;
}

// ---------------------------------------------------------------------------
// Edge head via MFMA: grid-stride with DEPTH-3 z/ep prefetch.
__global__ __launch_bounds__(256) void k_edge(
    const ushort_t* __restrict__ zbf, const int* __restrict__ ep,
    const ushort_t* __restrict__ w1bf, const float* __restrict__ b1,
    const ushort_t* __restrict__ w2bf, const float* __restrict__ b2,
    const float* __restrict__ W3, const float* __restrict__ b3,
    float* __restrict__ out)
{
    __shared__ ushort_t a1lds[4][16 * 64];
    const int tid  = threadIdx.x;
    const int lane = tid & 63;
    const int e    = lane & 15;
    const int c    = lane >> 4;
    ushort_t* lds  = &a1lds[tid >> 6][0];
    const uint_t swz = (uint_t)((e & 7) << 4);

    bf16x8 w1f[4][4];
    #pragma unroll
    for (int mt = 0; mt < 4; ++mt)
        #pragma unroll
        for (int ks = 0; ks < 4; ++ks)
            w1f[mt][ks] = *(const bf16x8*)(w1bf + (mt * 16 + e) * 128 + ks * 32 + c * 8);

    bf16x8 w2f[2][2];
    #pragma unroll
    for (int mt2 = 0; mt2 < 2; ++mt2)
        #pragma unroll
        for (int ks2 = 0; ks2 < 2; ++ks2)
            w2f[mt2][ks2] = *(const bf16x8*)(w2bf + (mt2 * 16 + e) * 64 + ks2 * 32 + c * 8);

    f32x4 bias1[4];
    #pragma unroll
    for (int mt = 0; mt < 4; ++mt) bias1[mt] = *(const f32x4*)(b1 + mt * 16 + c * 4);
    f32x4 bias2[2];
    #pragma unroll
    for (int mt2 = 0; mt2 < 2; ++mt2) bias2[mt2] = *(const f32x4*)(b2 + mt2 * 16 + c * 4);
    f32x4 w3v[2];
    #pragma unroll
    for (int mt2 = 0; mt2 < 2; ++mt2) w3v[mt2] = *(const f32x4*)(W3 + mt2 * 16 + c * 4);
    const float b3v = b3[0];

    const int nw = (gridDim.x * blockDim.x) >> 6;
    const int NT = NE / 16;

#define LOADZ(T, dst)                                                         \
    {                                                                         \
        int p = (T) * 16 + e;                                                 \
        int ni = ep[p];                                                       \
        int nj = ep[NE + p];                                                  \
        const ushort_t* zi = zbf + (size_t)ni * DOUT;                         \
        const ushort_t* zj = zbf + (size_t)nj * DOUT;                         \
        dst[0] = *(const bf16x8*)(zi + c * 8);                                \
        dst[1] = *(const bf16x8*)(zi + 32 + c * 8);                           \
        dst[2] = *(const bf16x8*)(zj + c * 8);                                \
        dst[3] = *(const bf16x8*)(zj + 32 + c * 8);                           \
    }

#define COMPUTE(T, bfr)                                                       \
    {                                                                         \
        f32x4 acc[4];                                                         \
        _Pragma("unroll")                                                     \
        for (int mt = 0; mt < 4; ++mt) acc[mt] = bias1[mt];                   \
        _Pragma("unroll")                                                     \
        for (int ks = 0; ks < 4; ++ks)                                        \
            _Pragma("unroll")                                                 \
            for (int mt = 0; mt < 4; ++mt)                                    \
                acc[mt] = __builtin_amdgcn_mfma_f32_16x16x32_bf16(            \
                    w1f[mt][ks], bfr[ks], acc[mt], 0, 0, 0);                  \
        _Pragma("unroll")                                                     \
        for (int mt = 0; mt < 4; ++mt) {                                      \
            uint_t lo = pk2bf(fmaxf(acc[mt][0], 0.f), fmaxf(acc[mt][1], 0.f));\
            uint_t hi = pk2bf(fmaxf(acc[mt][2], 0.f), fmaxf(acc[mt][3], 0.f));\
            uint_t off = (uint_t)(e * 128 + mt * 32 + c * 8) ^ swz;           \
            *(uint2*)((char*)lds + off) = make_uint2(lo, hi);                 \
        }                                                                     \
        bf16x8 b2f[2];                                                        \
        _Pragma("unroll")                                                     \
        for (int ks2 = 0; ks2 < 2; ++ks2) {                                   \
            uint_t off = (uint_t)(e * 128 + ks2 * 64 + c * 16) ^ swz;         \
            b2f[ks2] = *(const bf16x8*)((const char*)lds + off);              \
        }                                                                     \
        f32x4 a2[2];                                                          \
        _Pragma("unroll")                                                     \
        for (int mt2 = 0; mt2 < 2; ++mt2) a2[mt2] = bias2[mt2];               \
        _Pragma("unroll")                                                     \
        for (int ks2 = 0; ks2 < 2; ++ks2)                                     \
            _Pragma("unroll")                                                 \
            for (int mt2 = 0; mt2 < 2; ++mt2)                                 \
                a2[mt2] = __builtin_amdgcn_mfma_f32_16x16x32_bf16(            \
                    w2f[mt2][ks2], b2f[ks2], a2[mt2], 0, 0, 0);               \
        float t3 = b3v;                                                       \
        _Pragma("unroll")                                                     \
        for (int mt2 = 0; mt2 < 2; ++mt2)                                     \
            _Pragma("unroll")                                                 \
            for (int r = 0; r < 4; ++r)                                       \
                t3 += fmaxf(a2[mt2][r], 0.f) * w3v[mt2][r];                   \
        t3 += __shfl_xor(t3, 16);                                             \
        t3 += __shfl_xor(t3, 32);                                             \
        if (lane < 16) {                                                      \
            float ex = __expf(-t3);                                           \
            out[(T) * 16 + lane] = __builtin_amdgcn_rcpf(1.f + ex);           \
        }                                                                     \
    }

    bf16x8 zA[4], zB[4], zC[4];
    int ta = (blockIdx.x * blockDim.x + tid) >> 6;    // wave id
    if (ta >= NT) return;
    int tb = ta + nw;
    int tc = tb + nw;
    LOADZ(ta, zA);
    if (tb < NT) LOADZ(tb, zB);
    if (tc < NT) LOADZ(tc, zC);
    while (true) {
        COMPUTE(ta, zA);
        ta += 3 * nw;
        if (ta < NT) LOADZ(ta, zA);
        if (tb >= NT) break;
        COMPUTE(tb, zB);
        tb += 3 * nw;
        if (tb < NT) LOADZ(tb, zB);
        if (tc >= NT) break;
        COMPUTE(tc, zC);
        tc += 3 * nw;
        if (tc < NT) LOADZ(tc, zC);
        if (ta >= NT) break;
    }

#undef LOADZ
#undef COMPUTE
}

// ---------------------------------------------------------------------------
extern "C" void kernel_launch(void* const* d_in, const int* in_sizes, int n_in,
                              void* d_out, int out_size, void* d_ws, size_t ws_size,
                              hipStream_t stream)
{
    const float* x     = (const float*)d_in[0];
    const int*   ei    = (const int*)d_in[1];
    const int*   ep    = (const int*)d_in[2];
    const float* c1_Wl = (const float*)d_in[3];
    const float* c1_bl = (const float*)d_in[4];
    const float* c1_Wr = (const float*)d_in[5];
    const float* bn_g  = (const float*)d_in[6];
    const float* bn_b  = (const float*)d_in[7];
    const float* bn_m  = (const float*)d_in[8];
    const float* bn_v  = (const float*)d_in[9];
    const float* c2_Wl = (const float*)d_in[10];
    const float* c2_bl = (const float*)d_in[11];
    const float* c2_Wr = (const float*)d_in[12];
    const float* e_W1  = (const float*)d_in[13];
    const float* e_b1  = (const float*)d_in[14];
    const float* e_W2  = (const float*)d_in[15];
    const float* e_b2  = (const float*)d_in[16];
    const float* e_W3  = (const float*)d_in[17];
    const float* e_b3  = (const float*)d_in[18];
    float* out = (float*)d_out;

    _Float16* xh    = (_Float16*)d_ws;
    _Float16* hwbuf = xh + (size_t)NN * DIN;
    _Float16* hh    = hwbuf + (size_t)NN * DIN;
    ushort_t* zbf   = (ushort_t*)(hh + (size_t)NN * DHID);
    _Float16* w1cat = (_Float16*)(zbf + (size_t)NN * DOUT);
    _Float16* w2cat = w1cat + 128 * 256;
    ushort_t* w1bf  = (ushort_t*)(w2cat + 64 * 256);
    ushort_t* w2bf  = w1bf + 64 * 128;
    float*    bnsc  = (float*)(w2bf + 32 * 64);
    float*    bnsh  = bnsc + 128;
    int*      deg     = (int*)(bnsh + 128);
    int*      cursor  = deg + 50048;
    int*      rowptr  = cursor + 50048;
    int*      csr_src = rowptr + 50052;
    int*      part    = csr_src + 800000;

    hipMemsetAsync(deg, 0, (size_t)(50048 * 2) * sizeof(int), stream);

    k_deg_xcast<<<6250, 256, 0, stream>>>(ei, deg, x, xh);
    k_scan1_prep<<<50, 256, 0, stream>>>(deg, part,
                                         c1_Wl, c1_Wr, c2_Wl, c2_Wr,
                                         bn_g, bn_b, bn_m, bn_v, e_W1, e_W2,
                                         w1cat, w2cat, w1bf, w2bf, bnsc, bnsh);
    k_scan3<<<49, 256, 0, stream>>>(deg, part, rowptr);
    k_fill <<<3125, 256, 0, stream>>>(ei, rowptr, cursor, csr_src);

    k_gconv1<<<3125, 256, 0, stream>>>(xh, rowptr, csr_src, w1cat, c1_bl,
                                       bnsc, bnsh, w2cat, hh, hwbuf);
    k_gconv2<<<3125, 256, 0, stream>>>(hh, hwbuf, rowptr, csr_src, w2cat, c2_bl, zbf);

    k_edge<<<1024, 256, 0, stream>>>(zbf, ep, w1bf, e_b1, w2bf, e_b2,
                                     e_W3, e_b3, out);
}

// Round 18
// 247.940 us; speedup vs baseline: 1.1532x; 1.1317x over previous
//
#include <hip/hip_runtime.h>
#include <hip/hip_bf16.h>
#include <math.h>

#define NN 50000
#define NE 800000
#define DIN 128
#define DHID 128
#define DOUT 64
#define BN_EPS 1e-5f

typedef __attribute__((ext_vector_type(8))) short bf16x8;
typedef __attribute__((ext_vector_type(8))) _Float16 f16x8;
typedef __attribute__((ext_vector_type(4))) _Float16 f16x4;
typedef __attribute__((ext_vector_type(2))) _Float16 f16x2;
typedef __attribute__((ext_vector_type(4))) float f32x4;
typedef unsigned short ushort_t;
typedef unsigned int uint_t;

__device__ __forceinline__ ushort_t f2bf(float f) {
    uint_t u = __float_as_uint(f);
    uint_t r = (u + 0x7FFFu + ((u >> 16) & 1u)) >> 16;   // RNE
    return (ushort_t)r;
}

__device__ __forceinline__ uint_t pk2bf(float a, float b) {
    __hip_bfloat16 x = __float2bfloat16(a);
    __hip_bfloat16 y = __float2bfloat16(b);
    ushort_t ux = *reinterpret_cast<ushort_t*>(&x);
    ushort_t uy = *reinterpret_cast<ushort_t*>(&y);
    return (uint_t)ux | ((uint_t)uy << 16);
}

// ---------------------------------------------------------------------------
// Fused: blocks [0,3125) histogram dst degrees AND record per-edge slot
// (atomicAdd return), removing the cursor atomic from k_fill.
// Blocks [3125,6250): cast x->fp16.
__global__ __launch_bounds__(256) void k_deg_xcast(
    const int* __restrict__ ei, int* __restrict__ deg, int* __restrict__ slot,
    const float* __restrict__ x, _Float16* __restrict__ xh)
{
    int b = blockIdx.x;
    if (b < 3125) {
        int e = b * 256 + threadIdx.x;
        slot[e] = atomicAdd(deg + ei[NE + e], 1);
    } else {
        int i = (b - 3125) * 256 + threadIdx.x;
        const float4* src = (const float4*)x + (size_t)i * 2;
        float4 a = src[0], c = src[1];
        f16x8 o;
        o[0] = (_Float16)a.x; o[1] = (_Float16)a.y; o[2] = (_Float16)a.z; o[3] = (_Float16)a.w;
        o[4] = (_Float16)c.x; o[5] = (_Float16)c.y; o[6] = (_Float16)c.z; o[7] = (_Float16)c.w;
        *(f16x8*)(xh + (size_t)i * 8) = o;
    }
}

// ---------------------------------------------------------------------------
// Scan stage 1 (blocks 0..48) + weight prep (block 49).
__global__ __launch_bounds__(256) void k_scan1_prep(
    const int* __restrict__ deg, int* __restrict__ part,
    const float* __restrict__ c1_Wl, const float* __restrict__ c1_Wr,
    const float* __restrict__ c2_Wl, const float* __restrict__ c2_Wr,
    const float* __restrict__ gam, const float* __restrict__ bet,
    const float* __restrict__ bmean, const float* __restrict__ bvar,
    const float* __restrict__ eW1, const float* __restrict__ eW2,
    _Float16* __restrict__ w1cat, _Float16* __restrict__ w2cat,
    ushort_t* __restrict__ w1bf, ushort_t* __restrict__ w2bf,
    float* __restrict__ bnsc, float* __restrict__ bnsh)
{
    int t = threadIdx.x;
    if (blockIdx.x < 49) {
        __shared__ int s[256];
        int g = blockIdx.x * 256 + t;
        int v = 0;
        if (g < 12500) { int4 d = ((const int4*)deg)[g]; v = d.x + d.y + d.z + d.w; }
        s[t] = v;
        __syncthreads();
        #pragma unroll
        for (int off = 128; off > 0; off >>= 1) {
            if (t < off) s[t] += s[t + off];
            __syncthreads();
        }
        if (t == 0) part[blockIdx.x] = s[0];
    } else {
        for (int i = t; i < 128 * 128; i += 256) {
            int row = i >> 7, k = i & 127;
            w1cat[row * 256 + k]       = (_Float16)c1_Wl[i];
            w1cat[row * 256 + 128 + k] = (_Float16)c1_Wr[i];
        }
        for (int i = t; i < 64 * 128; i += 256) {
            int row = i >> 7, k = i & 127;
            w2cat[row * 256 + k]       = (_Float16)c2_Wl[i];
            w2cat[row * 256 + 128 + k] = (_Float16)c2_Wr[i];
        }
        for (int i = t; i < 64 * 128; i += 256) w1bf[i] = f2bf(eW1[i]);
        for (int i = t; i < 32 * 64; i += 256)  w2bf[i] = f2bf(eW2[i]);
        for (int i = t; i < 128; i += 256) {
            float s = gam[i] * rsqrtf(bvar[i] + BN_EPS);
            bnsc[i] = s;
            bnsh[i] = bet[i] - bmean[i] * s;
        }
    }
}

// Scan stage 2: per-block exclusive scan + block offset.
__global__ __launch_bounds__(256) void k_scan3(
    const int* __restrict__ deg, const int* __restrict__ part, int* __restrict__ rowptr)
{
    __shared__ int s[256];
    __shared__ int p[64];
    int t = threadIdx.x;
    int b = blockIdx.x;
    int g = b * 256 + t;
    int4 d = make_int4(0, 0, 0, 0);
    if (g < 12500) d = ((const int4*)deg)[g];
    int sum4 = d.x + d.y + d.z + d.w;
    s[t] = sum4;
    if (t < 49) p[t] = part[t];
    __syncthreads();
    #pragma unroll
    for (int off = 1; off < 256; off <<= 1) {
        int v = (t >= off) ? s[t - off] : 0;
        __syncthreads();
        s[t] += v;
        __syncthreads();
    }
    int blockoff = 0;
    for (int i = 0; i < b; ++i) blockoff += p[i];
    int off0 = blockoff + s[t] - sum4;
    if (g < 12500) {
        int4 o;
        o.x = off0;
        o.y = off0 + d.x;
        o.z = o.y + d.y;
        o.w = o.z + d.z;
        ((int4*)rowptr)[g] = o;
        if (g == 12499) rowptr[NN] = o.w + d.w;
    }
}

// Fill CSR column (src) array — atomic-free (slot precomputed in k_deg_xcast).
__global__ __launch_bounds__(256) void k_fill(
    const int* __restrict__ ei, const int* __restrict__ rowptr,
    const int* __restrict__ slot, int* __restrict__ csr_src)
{
    int e = blockIdx.x * blockDim.x + threadIdx.x;
    if (e >= NE) return;
    int dst = ei[NE + e];
    csr_src[rowptr[dst] + slot[e]] = ei[e];
}

// ---------------------------------------------------------------------------
// 128-dim gather (proven 8-deep form): wave gathers 4 nodes' means into a
// swizzled fp16 LDS tile. f16x2/lane (full 256B row per instruction).
#define GATHER4_128(feat)                                                      \
    {                                                                          \
        _Pragma("unroll 1")                                                    \
        for (int q = 0; q < 4; ++q) {                                          \
            int n = w * 4 + q;                                                 \
            int node4 = tile * 16 + n;                                         \
            int beg = __builtin_amdgcn_readfirstlane(rowptr[node4]);           \
            int end = __builtin_amdgcn_readfirstlane(rowptr[node4 + 1]);       \
            float2 a0 = {0.f,0.f}, a1 = {0.f,0.f}, a2 = {0.f,0.f}, a3 = {0.f,0.f}; \
            float2 a4 = {0.f,0.f}, a5 = {0.f,0.f}, a6 = {0.f,0.f}, a7 = {0.f,0.f}; \
            int j = beg;                                                       \
            for (; j + 7 < end; j += 8) {                                      \
                int s0 = csr_src[j];     int s1 = csr_src[j + 1];              \
                int s2 = csr_src[j + 2]; int s3 = csr_src[j + 3];              \
                int s4 = csr_src[j + 4]; int s5 = csr_src[j + 5];              \
                int s6 = csr_src[j + 6]; int s7 = csr_src[j + 7];              \
                f16x2 v0 = *(const f16x2*)(feat + (size_t)s0 * 128 + lane * 2);\
                f16x2 v1 = *(const f16x2*)(feat + (size_t)s1 * 128 + lane * 2);\
                f16x2 v2 = *(const f16x2*)(feat + (size_t)s2 * 128 + lane * 2);\
                f16x2 v3 = *(const f16x2*)(feat + (size_t)s3 * 128 + lane * 2);\
                f16x2 v4 = *(const f16x2*)(feat + (size_t)s4 * 128 + lane * 2);\
                f16x2 v5 = *(const f16x2*)(feat + (size_t)s5 * 128 + lane * 2);\
                f16x2 v6 = *(const f16x2*)(feat + (size_t)s6 * 128 + lane * 2);\
                f16x2 v7 = *(const f16x2*)(feat + (size_t)s7 * 128 + lane * 2);\
                a0.x += (float)v0[0]; a0.y += (float)v0[1];                    \
                a1.x += (float)v1[0]; a1.y += (float)v1[1];                    \
                a2.x += (float)v2[0]; a2.y += (float)v2[1];                    \
                a3.x += (float)v3[0]; a3.y += (float)v3[1];                    \
                a4.x += (float)v4[0]; a4.y += (float)v4[1];                    \
                a5.x += (float)v5[0]; a5.y += (float)v5[1];                    \
                a6.x += (float)v6[0]; a6.y += (float)v6[1];                    \
                a7.x += (float)v7[0]; a7.y += (float)v7[1];                    \
            }                                                                  \
            for (; j + 1 < end; j += 2) {                                      \
                int s0 = csr_src[j];                                           \
                int s1 = csr_src[j + 1];                                       \
                f16x2 v0 = *(const f16x2*)(feat + (size_t)s0 * 128 + lane * 2);\
                f16x2 v1 = *(const f16x2*)(feat + (size_t)s1 * 128 + lane * 2);\
                a0.x += (float)v0[0]; a0.y += (float)v0[1];                    \
                a1.x += (float)v1[0]; a1.y += (float)v1[1];                    \
            }                                                                  \
            if (j < end) {                                                     \
                int s0 = csr_src[j];                                           \
                f16x2 v0 = *(const f16x2*)(feat + (size_t)s0 * 128 + lane * 2);\
                a0.x += (float)v0[0]; a0.y += (float)v0[1];                    \
            }                                                                  \
            float inv = 1.0f / fmaxf((float)(end - beg), 1.0f);                \
            f16x2 o;                                                           \
            o[0] = (_Float16)((a0.x + a1.x + a2.x + a3.x + a4.x + a5.x + a6.x + a7.x) * inv); \
            o[1] = (_Float16)((a0.y + a1.y + a2.y + a3.y + a4.y + a5.y + a6.y + a7.y) * inv); \
            uint_t off = (uint_t)(n * 256 + lane * 4) ^ (uint_t)((n & 7) << 4);\
            *(f16x2*)((char*)mlds + off) = o;                                  \
        }                                                                      \
    }

// ---------------------------------------------------------------------------
// Fused gather-mean + Conv1 + hw epilogue. wf2 (hw weights) hoisted to the
// prologue so their L2 latency hides under the gather.
__global__ __launch_bounds__(256) void k_gconv1(
    const _Float16* __restrict__ xh, const int* __restrict__ rowptr,
    const int* __restrict__ csr_src,
    const _Float16* __restrict__ w1cat, const float* __restrict__ bl,
    const float* __restrict__ bnsc, const float* __restrict__ bnsh,
    const _Float16* __restrict__ w2cat, _Float16* __restrict__ hh,
    _Float16* __restrict__ hw)
{
    __shared__ _Float16 mlds[16 * 128];   // mean tile, 4 KB, swizzled
    __shared__ _Float16 hlds[16 * 128];   // h tile, 4 KB, swizzled
    const int tid = threadIdx.x;
    const int lane = tid & 63;
    const int w = tid >> 6;               // wave = col-chunk AND gather group
    const int tile = blockIdx.x;          // 3125 * 16 nodes
    const int e = lane & 15;
    const int c = lane >> 4;
    const int node = tile * 16 + e;

    // hoist ALL weight/feature loads before the gather (latency hiding)
    f16x8 wf[2][8];
    #pragma unroll
    for (int nt = 0; nt < 2; ++nt)
        #pragma unroll
        for (int ks = 0; ks < 8; ++ks)
            wf[nt][ks] = *(const f16x8*)(w1cat + (size_t)(w * 32 + nt * 16 + e) * 256 + ks * 32 + c * 8);
    f16x8 wf2[4];
    #pragma unroll
    for (int ks = 0; ks < 4; ++ks)
        wf2[ks] = *(const f16x8*)(w2cat + (size_t)(w * 16 + e) * 256 + ks * 32 + c * 8);
    f16x8 bfx[4];
    #pragma unroll
    for (int ks = 0; ks < 4; ++ks)
        bfx[ks] = *(const f16x8*)(xh + (size_t)node * 128 + ks * 32 + c * 8);
    f32x4 acc[2];
    #pragma unroll
    for (int nt = 0; nt < 2; ++nt)
        acc[nt] = *(const f32x4*)(bl + w * 32 + nt * 16 + c * 4);

    GATHER4_128(xh);
    __syncthreads();

    f16x8 bfm[4];
    #pragma unroll
    for (int ks = 0; ks < 4; ++ks) {
        uint_t off = (uint_t)(e * 256 + ks * 64 + c * 16) ^ (uint_t)((e & 7) << 4);
        bfm[ks] = *(const f16x8*)((const char*)mlds + off);
    }

    #pragma unroll
    for (int ks = 0; ks < 4; ++ks)
        #pragma unroll
        for (int nt = 0; nt < 2; ++nt)
            acc[nt] = __builtin_amdgcn_mfma_f32_16x16x32_f16(wf[nt][ks], bfm[ks], acc[nt], 0, 0, 0);
    #pragma unroll
    for (int ks = 0; ks < 4; ++ks)
        #pragma unroll
        for (int nt = 0; nt < 2; ++nt)
            acc[nt] = __builtin_amdgcn_mfma_f32_16x16x32_f16(wf[nt][ks + 4], bfx[ks], acc[nt], 0, 0, 0);

    #pragma unroll
    for (int nt = 0; nt < 2; ++nt) {
        int j0 = w * 32 + nt * 16 + c * 4;
        f32x4 sc = *(const f32x4*)(bnsc + j0);
        f32x4 sh = *(const f32x4*)(bnsh + j0);
        f16x4 o;
        #pragma unroll
        for (int r = 0; r < 4; ++r)
            o[r] = (_Float16)fmaxf(acc[nt][r] * sc[r] + sh[r], 0.f);
        *(f16x4*)(hh + (size_t)node * 128 + j0) = o;
        uint_t hoff = (uint_t)(e * 256 + j0 * 2) ^ (uint_t)((e & 7) << 4);
        *(f16x4*)((char*)hlds + hoff) = o;
    }

    __syncthreads();

    f16x8 bfh[4];
    #pragma unroll
    for (int ks = 0; ks < 4; ++ks) {
        uint_t off = (uint_t)(e * 256 + ks * 64 + c * 16) ^ (uint_t)((e & 7) << 4);
        bfh[ks] = *(const f16x8*)((const char*)hlds + off);
    }
    f32x4 acc2 = {0.f, 0.f, 0.f, 0.f};
    #pragma unroll
    for (int ks = 0; ks < 4; ++ks)
        acc2 = __builtin_amdgcn_mfma_f32_16x16x32_f16(wf2[ks], bfh[ks], acc2, 0, 0, 0);

    f16x4 ohw;
    #pragma unroll
    for (int r = 0; r < 4; ++r) ohw[r] = (_Float16)acc2[r];
    *(f16x4*)(hw + (size_t)node * 64 + w * 16 + c * 4) = ohw;
}

// ---------------------------------------------------------------------------
// Fused 64-dim gather-mean + Conv2 root side:
// z = mean(hw[src]) + bl + h@Wr.T  -> bf16. 8-deep gather (proven form).
__global__ __launch_bounds__(256) void k_gconv2(
    const _Float16* __restrict__ hh, const _Float16* __restrict__ hw,
    const int* __restrict__ rowptr, const int* __restrict__ csr_src,
    const _Float16* __restrict__ w2cat, const float* __restrict__ bl,
    ushort_t* __restrict__ zbf)
{
    __shared__ float mlds32[16 * 64];     // 4 KB f32, swizzled
    const int tid = threadIdx.x;
    const int lane = tid & 63;
    const int w = tid >> 6;
    const int tile = blockIdx.x;
    const int e = lane & 15;
    const int c = lane >> 4;
    const int node = tile * 16 + e;

    f16x8 wf[4];
    #pragma unroll
    for (int ks = 0; ks < 4; ++ks)
        wf[ks] = *(const f16x8*)(w2cat + (size_t)(w * 16 + e) * 256 + 128 + ks * 32 + c * 8);
    f16x8 bfx[4];
    #pragma unroll
    for (int ks = 0; ks < 4; ++ks)
        bfx[ks] = *(const f16x8*)(hh + (size_t)node * 128 + ks * 32 + c * 8);

    #pragma unroll 1
    for (int q = 0; q < 4; ++q) {
        int n = w * 4 + q;
        int node4 = tile * 16 + n;
        int beg = __builtin_amdgcn_readfirstlane(rowptr[node4]);
        int end = __builtin_amdgcn_readfirstlane(rowptr[node4 + 1]);
        float a0 = 0.f, a1 = 0.f, a2 = 0.f, a3 = 0.f;
        float a4 = 0.f, a5 = 0.f, a6 = 0.f, a7 = 0.f;
        int j = beg;
        for (; j + 7 < end; j += 8) {
            int s0 = csr_src[j];     int s1 = csr_src[j + 1];
            int s2 = csr_src[j + 2]; int s3 = csr_src[j + 3];
            int s4 = csr_src[j + 4]; int s5 = csr_src[j + 5];
            int s6 = csr_src[j + 6]; int s7 = csr_src[j + 7];
            a0 += (float)hw[(size_t)s0 * 64 + lane];
            a1 += (float)hw[(size_t)s1 * 64 + lane];
            a2 += (float)hw[(size_t)s2 * 64 + lane];
            a3 += (float)hw[(size_t)s3 * 64 + lane];
            a4 += (float)hw[(size_t)s4 * 64 + lane];
            a5 += (float)hw[(size_t)s5 * 64 + lane];
            a6 += (float)hw[(size_t)s6 * 64 + lane];
            a7 += (float)hw[(size_t)s7 * 64 + lane];
        }
        for (; j + 1 < end; j += 2) {
            int s0 = csr_src[j];
            int s1 = csr_src[j + 1];
            a0 += (float)hw[(size_t)s0 * 64 + lane];
            a1 += (float)hw[(size_t)s1 * 64 + lane];
        }
        if (j < end) {
            int s0 = csr_src[j];
            a0 += (float)hw[(size_t)s0 * 64 + lane];
        }
        float inv = 1.0f / fmaxf((float)(end - beg), 1.0f);
        float m = (a0 + a1 + a2 + a3 + a4 + a5 + a6 + a7) * inv;
        uint_t off = (uint_t)(n * 256 + lane * 4) ^ (uint_t)((n & 7) << 4);
        *(float*)((char*)mlds32 + off) = m;
    }
    __syncthreads();

    f32x4 acc = *(const f32x4*)(bl + w * 16 + c * 4);
    {
        uint_t off = (uint_t)(e * 256 + (w * 16 + c * 4) * 4) ^ (uint_t)((e & 7) << 4);
        f32x4 mv = *(const f32x4*)((const char*)mlds32 + off);
        acc[0] += mv[0]; acc[1] += mv[1]; acc[2] += mv[2]; acc[3] += mv[3];
    }

    #pragma unroll
    for (int ks = 0; ks < 4; ++ks)
        acc = __builtin_amdgcn_mfma_f32_16x16x32_f16(wf[ks], bfx[ks], acc, 0, 0, 0);

    int j0 = w * 16 + c * 4;
    uint2 pk;
    pk.x = pk2bf(acc[0], acc[1]);
    pk.y = pk2bf(acc[2], acc[3]);
    *(uint2*)(zbf + (size_t)node * 64 + j0) = pk;
}

// ---------------------------------------------------------------------------
// Edge head via MFMA: grid-stride with DEPTH-3 z/ep prefetch.
__global__ __launch_bounds__(256) void k_edge(
    const ushort_t* __restrict__ zbf, const int* __restrict__ ep,
    const ushort_t* __restrict__ w1bf, const float* __restrict__ b1,
    const ushort_t* __restrict__ w2bf, const float* __restrict__ b2,
    const float* __restrict__ W3, const float* __restrict__ b3,
    float* __restrict__ out)
{
    __shared__ ushort_t a1lds[4][16 * 64];
    const int tid  = threadIdx.x;
    const int lane = tid & 63;
    const int e    = lane & 15;
    const int c    = lane >> 4;
    ushort_t* lds  = &a1lds[tid >> 6][0];
    const uint_t swz = (uint_t)((e & 7) << 4);

    bf16x8 w1f[4][4];
    #pragma unroll
    for (int mt = 0; mt < 4; ++mt)
        #pragma unroll
        for (int ks = 0; ks < 4; ++ks)
            w1f[mt][ks] = *(const bf16x8*)(w1bf + (mt * 16 + e) * 128 + ks * 32 + c * 8);

    bf16x8 w2f[2][2];
    #pragma unroll
    for (int mt2 = 0; mt2 < 2; ++mt2)
        #pragma unroll
        for (int ks2 = 0; ks2 < 2; ++ks2)
            w2f[mt2][ks2] = *(const bf16x8*)(w2bf + (mt2 * 16 + e) * 64 + ks2 * 32 + c * 8);

    f32x4 bias1[4];
    #pragma unroll
    for (int mt = 0; mt < 4; ++mt) bias1[mt] = *(const f32x4*)(b1 + mt * 16 + c * 4);
    f32x4 bias2[2];
    #pragma unroll
    for (int mt2 = 0; mt2 < 2; ++mt2) bias2[mt2] = *(const f32x4*)(b2 + mt2 * 16 + c * 4);
    f32x4 w3v[2];
    #pragma unroll
    for (int mt2 = 0; mt2 < 2; ++mt2) w3v[mt2] = *(const f32x4*)(W3 + mt2 * 16 + c * 4);
    const float b3v = b3[0];

    const int nw = (gridDim.x * blockDim.x) >> 6;
    const int NT = NE / 16;

#define LOADZ(T, dst)                                                         \
    {                                                                         \
        int p = (T) * 16 + e;                                                 \
        int ni = ep[p];                                                       \
        int nj = ep[NE + p];                                                  \
        const ushort_t* zi = zbf + (size_t)ni * DOUT;                         \
        const ushort_t* zj = zbf + (size_t)nj * DOUT;                         \
        dst[0] = *(const bf16x8*)(zi + c * 8);                                \
        dst[1] = *(const bf16x8*)(zi + 32 + c * 8);                           \
        dst[2] = *(const bf16x8*)(zj + c * 8);                                \
        dst[3] = *(const bf16x8*)(zj + 32 + c * 8);                           \
    }

#define COMPUTE(T, bfr)                                                       \
    {                                                                         \
        f32x4 acc[4];                                                         \
        _Pragma("unroll")                                                     \
        for (int mt = 0; mt < 4; ++mt) acc[mt] = bias1[mt];                   \
        _Pragma("unroll")                                                     \
        for (int ks = 0; ks < 4; ++ks)                                        \
            _Pragma("unroll")                                                 \
            for (int mt = 0; mt < 4; ++mt)                                    \
                acc[mt] = __builtin_amdgcn_mfma_f32_16x16x32_bf16(            \
                    w1f[mt][ks], bfr[ks], acc[mt], 0, 0, 0);                  \
        _Pragma("unroll")                                                     \
        for (int mt = 0; mt < 4; ++mt) {                                      \
            uint_t lo = pk2bf(fmaxf(acc[mt][0], 0.f), fmaxf(acc[mt][1], 0.f));\
            uint_t hi = pk2bf(fmaxf(acc[mt][2], 0.f), fmaxf(acc[mt][3], 0.f));\
            uint_t off = (uint_t)(e * 128 + mt * 32 + c * 8) ^ swz;           \
            *(uint2*)((char*)lds + off) = make_uint2(lo, hi);                 \
        }                                                                     \
        bf16x8 b2f[2];                                                        \
        _Pragma("unroll")                                                     \
        for (int ks2 = 0; ks2 < 2; ++ks2) {                                   \
            uint_t off = (uint_t)(e * 128 + ks2 * 64 + c * 16) ^ swz;         \
            b2f[ks2] = *(const bf16x8*)((const char*)lds + off);              \
        }                                                                     \
        f32x4 a2[2];                                                          \
        _Pragma("unroll")                                                     \
        for (int mt2 = 0; mt2 < 2; ++mt2) a2[mt2] = bias2[mt2];               \
        _Pragma("unroll")                                                     \
        for (int ks2 = 0; ks2 < 2; ++ks2)                                     \
            _Pragma("unroll")                                                 \
            for (int mt2 = 0; mt2 < 2; ++mt2)                                 \
                a2[mt2] = __builtin_amdgcn_mfma_f32_16x16x32_bf16(            \
                    w2f[mt2][ks2], b2f[ks2], a2[mt2], 0, 0, 0);               \
        float t3 = b3v;                                                       \
        _Pragma("unroll")                                                     \
        for (int mt2 = 0; mt2 < 2; ++mt2)                                     \
            _Pragma("unroll")                                                 \
            for (int r = 0; r < 4; ++r)                                       \
                t3 += fmaxf(a2[mt2][r], 0.f) * w3v[mt2][r];                   \
        t3 += __shfl_xor(t3, 16);                                             \
        t3 += __shfl_xor(t3, 32);                                             \
        if (lane < 16) {                                                      \
            float ex = __expf(-t3);                                           \
            out[(T) * 16 + lane] = __builtin_amdgcn_rcpf(1.f + ex);           \
        }                                                                     \
    }

    bf16x8 zA[4], zB[4], zC[4];
    int ta = (blockIdx.x * blockDim.x + tid) >> 6;    // wave id
    if (ta >= NT) return;
    int tb = ta + nw;
    int tc = tb + nw;
    LOADZ(ta, zA);
    if (tb < NT) LOADZ(tb, zB);
    if (tc < NT) LOADZ(tc, zC);
    while (true) {
        COMPUTE(ta, zA);
        ta += 3 * nw;
        if (ta < NT) LOADZ(ta, zA);
        if (tb >= NT) break;
        COMPUTE(tb, zB);
        tb += 3 * nw;
        if (tb < NT) LOADZ(tb, zB);
        if (tc >= NT) break;
        COMPUTE(tc, zC);
        tc += 3 * nw;
        if (tc < NT) LOADZ(tc, zC);
        if (ta >= NT) break;
    }

#undef LOADZ
#undef COMPUTE
}

// ---------------------------------------------------------------------------
extern "C" void kernel_launch(void* const* d_in, const int* in_sizes, int n_in,
                              void* d_out, int out_size, void* d_ws, size_t ws_size,
                              hipStream_t stream)
{
    const float* x     = (const float*)d_in[0];
    const int*   ei    = (const int*)d_in[1];
    const int*   ep    = (const int*)d_in[2];
    const float* c1_Wl = (const float*)d_in[3];
    const float* c1_bl = (const float*)d_in[4];
    const float* c1_Wr = (const float*)d_in[5];
    const float* bn_g  = (const float*)d_in[6];
    const float* bn_b  = (const float*)d_in[7];
    const float* bn_m  = (const float*)d_in[8];
    const float* bn_v  = (const float*)d_in[9];
    const float* c2_Wl = (const float*)d_in[10];
    const float* c2_bl = (const float*)d_in[11];
    const float* c2_Wr = (const float*)d_in[12];
    const float* e_W1  = (const float*)d_in[13];
    const float* e_b1  = (const float*)d_in[14];
    const float* e_W2  = (const float*)d_in[15];
    const float* e_b2  = (const float*)d_in[16];
    const float* e_W3  = (const float*)d_in[17];
    const float* e_b3  = (const float*)d_in[18];
    float* out = (float*)d_out;

    _Float16* xh    = (_Float16*)d_ws;
    _Float16* hwbuf = xh + (size_t)NN * DIN;
    _Float16* hh    = hwbuf + (size_t)NN * DIN;
    ushort_t* zbf   = (ushort_t*)(hh + (size_t)NN * DHID);
    _Float16* w1cat = (_Float16*)(zbf + (size_t)NN * DOUT);
    _Float16* w2cat = w1cat + 128 * 256;
    ushort_t* w1bf  = (ushort_t*)(w2cat + 64 * 256);
    ushort_t* w2bf  = w1bf + 64 * 128;
    float*    bnsc  = (float*)(w2bf + 32 * 64);
    float*    bnsh  = bnsc + 128;
    int*      deg     = (int*)(bnsh + 128);
    int*      rowptr  = deg + 50052;
    int*      csr_src = rowptr + 50052;
    int*      part    = csr_src + 800000;
    int*      slot    = part + 64;

    hipMemsetAsync(deg, 0, (size_t)50052 * sizeof(int), stream);

    k_deg_xcast<<<6250, 256, 0, stream>>>(ei, deg, slot, x, xh);
    k_scan1_prep<<<50, 256, 0, stream>>>(deg, part,
                                         c1_Wl, c1_Wr, c2_Wl, c2_Wr,
                                         bn_g, bn_b, bn_m, bn_v, e_W1, e_W2,
                                         w1cat, w2cat, w1bf, w2bf, bnsc, bnsh);
    k_scan3<<<49, 256, 0, stream>>>(deg, part, rowptr);
    k_fill <<<3125, 256, 0, stream>>>(ei, rowptr, slot, csr_src);

    k_gconv1<<<3125, 256, 0, stream>>>(xh, rowptr, csr_src, w1cat, c1_bl,
                                       bnsc, bnsh, w2cat, hh, hwbuf);
    k_gconv2<<<3125, 256, 0, stream>>>(hh, hwbuf, rowptr, csr_src, w2cat, c2_bl, zbf);

    k_edge<<<1024, 256, 0, stream>>>(zbf, ep, w1bf, e_b1, w2bf, e_b2,
                                     e_W3, e_b3, out);
}

// Round 19
// 247.052 us; speedup vs baseline: 1.1573x; 1.0036x over previous
//
#include <hip/hip_runtime.h>
#include <hip/hip_bf16.h>
#include <math.h>

#define NN 50000
#define NE 800000
#define DIN 128
#define DHID 128
#define DOUT 64
#define BN_EPS 1e-5f

typedef __attribute__((ext_vector_type(8))) short bf16x8;
typedef __attribute__((ext_vector_type(8))) _Float16 f16x8;
typedef __attribute__((ext_vector_type(4))) _Float16 f16x4;
typedef __attribute__((ext_vector_type(2))) _Float16 f16x2;
typedef __attribute__((ext_vector_type(4))) float f32x4;
typedef unsigned short ushort_t;
typedef unsigned int uint_t;

__device__ __forceinline__ ushort_t f2bf(float f) {
    uint_t u = __float_as_uint(f);
    uint_t r = (u + 0x7FFFu + ((u >> 16) & 1u)) >> 16;   // RNE
    return (ushort_t)r;
}

__device__ __forceinline__ uint_t pk2bf(float a, float b) {
    __hip_bfloat16 x = __float2bfloat16(a);
    __hip_bfloat16 y = __float2bfloat16(b);
    ushort_t ux = *reinterpret_cast<ushort_t*>(&x);
    ushort_t uy = *reinterpret_cast<ushort_t*>(&y);
    return (uint_t)ux | ((uint_t)uy << 16);
}

// ---------------------------------------------------------------------------
// Fused: blocks [0,3125) histogram dst degrees AND record per-edge slot
// (atomicAdd return) -> k_fill becomes atomic-free.
// Blocks [3125,6250): cast x->fp16.
__global__ __launch_bounds__(256) void k_deg_xcast(
    const int* __restrict__ ei, int* __restrict__ deg, int* __restrict__ slot,
    const float* __restrict__ x, _Float16* __restrict__ xh)
{
    int b = blockIdx.x;
    if (b < 3125) {
        int e = b * 256 + threadIdx.x;
        slot[e] = atomicAdd(deg + ei[NE + e], 1);
    } else {
        int i = (b - 3125) * 256 + threadIdx.x;
        const float4* src = (const float4*)x + (size_t)i * 2;
        float4 a = src[0], c = src[1];
        f16x8 o;
        o[0] = (_Float16)a.x; o[1] = (_Float16)a.y; o[2] = (_Float16)a.z; o[3] = (_Float16)a.w;
        o[4] = (_Float16)c.x; o[5] = (_Float16)c.y; o[6] = (_Float16)c.z; o[7] = (_Float16)c.w;
        *(f16x8*)(xh + (size_t)i * 8) = o;
    }
}

// ---------------------------------------------------------------------------
// Scan stage 1 (blocks 0..48) + weight prep (block 49).
__global__ __launch_bounds__(256) void k_scan1_prep(
    const int* __restrict__ deg, int* __restrict__ part,
    const float* __restrict__ c1_Wl, const float* __restrict__ c1_Wr,
    const float* __restrict__ c2_Wl, const float* __restrict__ c2_Wr,
    const float* __restrict__ gam, const float* __restrict__ bet,
    const float* __restrict__ bmean, const float* __restrict__ bvar,
    const float* __restrict__ eW1, const float* __restrict__ eW2,
    _Float16* __restrict__ w1cat, _Float16* __restrict__ w2cat,
    ushort_t* __restrict__ w1bf, ushort_t* __restrict__ w2bf,
    float* __restrict__ bnsc, float* __restrict__ bnsh)
{
    int t = threadIdx.x;
    if (blockIdx.x < 49) {
        __shared__ int s[256];
        int g = blockIdx.x * 256 + t;
        int v = 0;
        if (g < 12500) { int4 d = ((const int4*)deg)[g]; v = d.x + d.y + d.z + d.w; }
        s[t] = v;
        __syncthreads();
        #pragma unroll
        for (int off = 128; off > 0; off >>= 1) {
            if (t < off) s[t] += s[t + off];
            __syncthreads();
        }
        if (t == 0) part[blockIdx.x] = s[0];
    } else {
        for (int i = t; i < 128 * 128; i += 256) {
            int row = i >> 7, k = i & 127;
            w1cat[row * 256 + k]       = (_Float16)c1_Wl[i];
            w1cat[row * 256 + 128 + k] = (_Float16)c1_Wr[i];
        }
        for (int i = t; i < 64 * 128; i += 256) {
            int row = i >> 7, k = i & 127;
            w2cat[row * 256 + k]       = (_Float16)c2_Wl[i];
            w2cat[row * 256 + 128 + k] = (_Float16)c2_Wr[i];
        }
        for (int i = t; i < 64 * 128; i += 256) w1bf[i] = f2bf(eW1[i]);
        for (int i = t; i < 32 * 64; i += 256)  w2bf[i] = f2bf(eW2[i]);
        for (int i = t; i < 128; i += 256) {
            float s = gam[i] * rsqrtf(bvar[i] + BN_EPS);
            bnsc[i] = s;
            bnsh[i] = bet[i] - bmean[i] * s;
        }
    }
}

// Scan stage 2: per-block exclusive scan + block offset.
__global__ __launch_bounds__(256) void k_scan3(
    const int* __restrict__ deg, const int* __restrict__ part, int* __restrict__ rowptr)
{
    __shared__ int s[256];
    __shared__ int p[64];
    int t = threadIdx.x;
    int b = blockIdx.x;
    int g = b * 256 + t;
    int4 d = make_int4(0, 0, 0, 0);
    if (g < 12500) d = ((const int4*)deg)[g];
    int sum4 = d.x + d.y + d.z + d.w;
    s[t] = sum4;
    if (t < 49) p[t] = part[t];
    __syncthreads();
    #pragma unroll
    for (int off = 1; off < 256; off <<= 1) {
        int v = (t >= off) ? s[t - off] : 0;
        __syncthreads();
        s[t] += v;
        __syncthreads();
    }
    int blockoff = 0;
    for (int i = 0; i < b; ++i) blockoff += p[i];
    int off0 = blockoff + s[t] - sum4;
    if (g < 12500) {
        int4 o;
        o.x = off0;
        o.y = off0 + d.x;
        o.z = o.y + d.y;
        o.w = o.z + d.z;
        ((int4*)rowptr)[g] = o;
        if (g == 12499) rowptr[NN] = o.w + d.w;
    }
}

// Fill CSR column (src) array — atomic-free (slot precomputed in k_deg_xcast).
__global__ __launch_bounds__(256) void k_fill(
    const int* __restrict__ ei, const int* __restrict__ rowptr,
    const int* __restrict__ slot, int* __restrict__ csr_src)
{
    int e = blockIdx.x * blockDim.x + threadIdx.x;
    if (e >= NE) return;
    int dst = ei[NE + e];
    csr_src[rowptr[dst] + slot[e]] = ei[e];
}

// ---------------------------------------------------------------------------
// 128-dim gather (proven 8-deep form, 68 µs): wave gathers 4 nodes' means
// into a swizzled fp16 LDS tile. f16x2/lane (full 256B row per instruction).
#define GATHER4_128(feat)                                                      \
    {                                                                          \
        _Pragma("unroll 1")                                                    \
        for (int q = 0; q < 4; ++q) {                                          \
            int n = w * 4 + q;                                                 \
            int node4 = tile * 16 + n;                                         \
            int beg = __builtin_amdgcn_readfirstlane(rowptr[node4]);           \
            int end = __builtin_amdgcn_readfirstlane(rowptr[node4 + 1]);       \
            float2 a0 = {0.f,0.f}, a1 = {0.f,0.f}, a2 = {0.f,0.f}, a3 = {0.f,0.f}; \
            float2 a4 = {0.f,0.f}, a5 = {0.f,0.f}, a6 = {0.f,0.f}, a7 = {0.f,0.f}; \
            int j = beg;                                                       \
            for (; j + 7 < end; j += 8) {                                      \
                int s0 = csr_src[j];     int s1 = csr_src[j + 1];              \
                int s2 = csr_src[j + 2]; int s3 = csr_src[j + 3];              \
                int s4 = csr_src[j + 4]; int s5 = csr_src[j + 5];              \
                int s6 = csr_src[j + 6]; int s7 = csr_src[j + 7];              \
                f16x2 v0 = *(const f16x2*)(feat + (size_t)s0 * 128 + lane * 2);\
                f16x2 v1 = *(const f16x2*)(feat + (size_t)s1 * 128 + lane * 2);\
                f16x2 v2 = *(const f16x2*)(feat + (size_t)s2 * 128 + lane * 2);\
                f16x2 v3 = *(const f16x2*)(feat + (size_t)s3 * 128 + lane * 2);\
                f16x2 v4 = *(const f16x2*)(feat + (size_t)s4 * 128 + lane * 2);\
                f16x2 v5 = *(const f16x2*)(feat + (size_t)s5 * 128 + lane * 2);\
                f16x2 v6 = *(const f16x2*)(feat + (size_t)s6 * 128 + lane * 2);\
                f16x2 v7 = *(const f16x2*)(feat + (size_t)s7 * 128 + lane * 2);\
                a0.x += (float)v0[0]; a0.y += (float)v0[1];                    \
                a1.x += (float)v1[0]; a1.y += (float)v1[1];                    \
                a2.x += (float)v2[0]; a2.y += (float)v2[1];                    \
                a3.x += (float)v3[0]; a3.y += (float)v3[1];                    \
                a4.x += (float)v4[0]; a4.y += (float)v4[1];                    \
                a5.x += (float)v5[0]; a5.y += (float)v5[1];                    \
                a6.x += (float)v6[0]; a6.y += (float)v6[1];                    \
                a7.x += (float)v7[0]; a7.y += (float)v7[1];                    \
            }                                                                  \
            for (; j + 1 < end; j += 2) {                                      \
                int s0 = csr_src[j];                                           \
                int s1 = csr_src[j + 1];                                       \
                f16x2 v0 = *(const f16x2*)(feat + (size_t)s0 * 128 + lane * 2);\
                f16x2 v1 = *(const f16x2*)(feat + (size_t)s1 * 128 + lane * 2);\
                a0.x += (float)v0[0]; a0.y += (float)v0[1];                    \
                a1.x += (float)v1[0]; a1.y += (float)v1[1];                    \
            }                                                                  \
            if (j < end) {                                                     \
                int s0 = csr_src[j];                                           \
                f16x2 v0 = *(const f16x2*)(feat + (size_t)s0 * 128 + lane * 2);\
                a0.x += (float)v0[0]; a0.y += (float)v0[1];                    \
            }                                                                  \
            float inv = 1.0f / fmaxf((float)(end - beg), 1.0f);                \
            f16x2 o;                                                           \
            o[0] = (_Float16)((a0.x + a1.x + a2.x + a3.x + a4.x + a5.x + a6.x + a7.x) * inv); \
            o[1] = (_Float16)((a0.y + a1.y + a2.y + a3.y + a4.y + a5.y + a6.y + a7.y) * inv); \
            uint_t off = (uint_t)(n * 256 + lane * 4) ^ (uint_t)((n & 7) << 4);\
            *(f16x2*)((char*)mlds + off) = o;                                  \
        }                                                                      \
    }

// Fused gather-mean + Conv1 (round-13 proven form, 68 µs):
// h = relu(BN(mean@Wl.T + bl + x@Wr.T)).
__global__ __launch_bounds__(256) void k_gconv1(
    const _Float16* __restrict__ xh, const int* __restrict__ rowptr,
    const int* __restrict__ csr_src,
    const _Float16* __restrict__ w1cat, const float* __restrict__ bl,
    const float* __restrict__ bnsc, const float* __restrict__ bnsh,
    _Float16* __restrict__ hh)
{
    __shared__ _Float16 mlds[16 * 128];   // 4 KB, swizzled
    const int tid = threadIdx.x;
    const int lane = tid & 63;
    const int w = tid >> 6;
    const int tile = blockIdx.x;
    const int e = lane & 15;
    const int c = lane >> 4;
    const int node = tile * 16 + e;

    f16x8 wf[2][8];
    #pragma unroll
    for (int nt = 0; nt < 2; ++nt)
        #pragma unroll
        for (int ks = 0; ks < 8; ++ks)
            wf[nt][ks] = *(const f16x8*)(w1cat + (size_t)(w * 32 + nt * 16 + e) * 256 + ks * 32 + c * 8);
    f16x8 bfx[4];
    #pragma unroll
    for (int ks = 0; ks < 4; ++ks)
        bfx[ks] = *(const f16x8*)(xh + (size_t)node * 128 + ks * 32 + c * 8);
    f32x4 acc[2];
    #pragma unroll
    for (int nt = 0; nt < 2; ++nt)
        acc[nt] = *(const f32x4*)(bl + w * 32 + nt * 16 + c * 4);

    GATHER4_128(xh);
    __syncthreads();

    f16x8 bfm[4];
    #pragma unroll
    for (int ks = 0; ks < 4; ++ks) {
        uint_t off = (uint_t)(e * 256 + ks * 64 + c * 16) ^ (uint_t)((e & 7) << 4);
        bfm[ks] = *(const f16x8*)((const char*)mlds + off);
    }

    #pragma unroll
    for (int ks = 0; ks < 4; ++ks)
        #pragma unroll
        for (int nt = 0; nt < 2; ++nt)
            acc[nt] = __builtin_amdgcn_mfma_f32_16x16x32_f16(wf[nt][ks], bfm[ks], acc[nt], 0, 0, 0);
    #pragma unroll
    for (int ks = 0; ks < 4; ++ks)
        #pragma unroll
        for (int nt = 0; nt < 2; ++nt)
            acc[nt] = __builtin_amdgcn_mfma_f32_16x16x32_f16(wf[nt][ks + 4], bfx[ks], acc[nt], 0, 0, 0);

    #pragma unroll
    for (int nt = 0; nt < 2; ++nt) {
        int j0 = w * 32 + nt * 16 + c * 4;
        f32x4 sc = *(const f32x4*)(bnsc + j0);
        f32x4 sh = *(const f32x4*)(bnsh + j0);
        f16x4 o;
        #pragma unroll
        for (int r = 0; r < 4; ++r)
            o[r] = (_Float16)fmaxf(acc[nt][r] * sc[r] + sh[r], 0.f);
        *(f16x4*)(hh + (size_t)node * 128 + j0) = o;
    }
}

// ---------------------------------------------------------------------------
// hw = h @ c2_Wl.T (50k x 64, fp16) — streaming MFMA, separate kernel.
__global__ __launch_bounds__(256) void k_hw(
    const _Float16* __restrict__ hh, const _Float16* __restrict__ w2cat,
    _Float16* __restrict__ hw)
{
    const int tid = threadIdx.x;
    const int lane = tid & 63;
    const int e = lane & 15;
    const int c = lane >> 4;
    const int w = tid >> 6;               // 4 waves = 4 col-chunks of 16
    const int node = blockIdx.x * 16 + e;

    f16x8 wf[4];
    #pragma unroll
    for (int ks = 0; ks < 4; ++ks)
        wf[ks] = *(const f16x8*)(w2cat + (size_t)(w * 16 + e) * 256 + ks * 32 + c * 8);  // Wl half
    f16x8 bf[4];
    #pragma unroll
    for (int ks = 0; ks < 4; ++ks)
        bf[ks] = *(const f16x8*)(hh + (size_t)node * 128 + ks * 32 + c * 8);

    f32x4 acc = {0.f, 0.f, 0.f, 0.f};
    #pragma unroll
    for (int ks = 0; ks < 4; ++ks)
        acc = __builtin_amdgcn_mfma_f32_16x16x32_f16(wf[ks], bf[ks], acc, 0, 0, 0);

    f16x4 o;
    #pragma unroll
    for (int r = 0; r < 4; ++r) o[r] = (_Float16)acc[r];
    *(f16x4*)(hw + (size_t)node * 64 + w * 16 + c * 4) = o;
}

// ---------------------------------------------------------------------------
// Fused 64-dim gather-mean + Conv2 root side:
// z = mean(hw[src]) + bl + h@Wr.T  -> bf16. 8-deep gather (proven form).
__global__ __launch_bounds__(256) void k_gconv2(
    const _Float16* __restrict__ hh, const _Float16* __restrict__ hw,
    const int* __restrict__ rowptr, const int* __restrict__ csr_src,
    const _Float16* __restrict__ w2cat, const float* __restrict__ bl,
    ushort_t* __restrict__ zbf)
{
    __shared__ float mlds32[16 * 64];     // 4 KB f32, swizzled
    const int tid = threadIdx.x;
    const int lane = tid & 63;
    const int w = tid >> 6;
    const int tile = blockIdx.x;
    const int e = lane & 15;
    const int c = lane >> 4;
    const int node = tile * 16 + e;

    f16x8 wf[4];
    #pragma unroll
    for (int ks = 0; ks < 4; ++ks)
        wf[ks] = *(const f16x8*)(w2cat + (size_t)(w * 16 + e) * 256 + 128 + ks * 32 + c * 8);
    f16x8 bfx[4];
    #pragma unroll
    for (int ks = 0; ks < 4; ++ks)
        bfx[ks] = *(const f16x8*)(hh + (size_t)node * 128 + ks * 32 + c * 8);

    #pragma unroll 1
    for (int q = 0; q < 4; ++q) {
        int n = w * 4 + q;
        int node4 = tile * 16 + n;
        int beg = __builtin_amdgcn_readfirstlane(rowptr[node4]);
        int end = __builtin_amdgcn_readfirstlane(rowptr[node4 + 1]);
        float a0 = 0.f, a1 = 0.f, a2 = 0.f, a3 = 0.f;
        float a4 = 0.f, a5 = 0.f, a6 = 0.f, a7 = 0.f;
        int j = beg;
        for (; j + 7 < end; j += 8) {
            int s0 = csr_src[j];     int s1 = csr_src[j + 1];
            int s2 = csr_src[j + 2]; int s3 = csr_src[j + 3];
            int s4 = csr_src[j + 4]; int s5 = csr_src[j + 5];
            int s6 = csr_src[j + 6]; int s7 = csr_src[j + 7];
            a0 += (float)hw[(size_t)s0 * 64 + lane];
            a1 += (float)hw[(size_t)s1 * 64 + lane];
            a2 += (float)hw[(size_t)s2 * 64 + lane];
            a3 += (float)hw[(size_t)s3 * 64 + lane];
            a4 += (float)hw[(size_t)s4 * 64 + lane];
            a5 += (float)hw[(size_t)s5 * 64 + lane];
            a6 += (float)hw[(size_t)s6 * 64 + lane];
            a7 += (float)hw[(size_t)s7 * 64 + lane];
        }
        for (; j + 1 < end; j += 2) {
            int s0 = csr_src[j];
            int s1 = csr_src[j + 1];
            a0 += (float)hw[(size_t)s0 * 64 + lane];
            a1 += (float)hw[(size_t)s1 * 64 + lane];
        }
        if (j < end) {
            int s0 = csr_src[j];
            a0 += (float)hw[(size_t)s0 * 64 + lane];
        }
        float inv = 1.0f / fmaxf((float)(end - beg), 1.0f);
        float m = (a0 + a1 + a2 + a3 + a4 + a5 + a6 + a7) * inv;
        uint_t off = (uint_t)(n * 256 + lane * 4) ^ (uint_t)((n & 7) << 4);
        *(float*)((char*)mlds32 + off) = m;
    }
    __syncthreads();

    f32x4 acc = *(const f32x4*)(bl + w * 16 + c * 4);
    {
        uint_t off = (uint_t)(e * 256 + (w * 16 + c * 4) * 4) ^ (uint_t)((e & 7) << 4);
        f32x4 mv = *(const f32x4*)((const char*)mlds32 + off);
        acc[0] += mv[0]; acc[1] += mv[1]; acc[2] += mv[2]; acc[3] += mv[3];
    }

    #pragma unroll
    for (int ks = 0; ks < 4; ++ks)
        acc = __builtin_amdgcn_mfma_f32_16x16x32_f16(wf[ks], bfx[ks], acc, 0, 0, 0);

    int j0 = w * 16 + c * 4;
    uint2 pk;
    pk.x = pk2bf(acc[0], acc[1]);
    pk.y = pk2bf(acc[2], acc[3]);
    *(uint2*)(zbf + (size_t)node * 64 + j0) = pk;
}

// ---------------------------------------------------------------------------
// Edge head via MFMA: grid-stride with DEPTH-3 z/ep prefetch.
__global__ __launch_bounds__(256) void k_edge(
    const ushort_t* __restrict__ zbf, const int* __restrict__ ep,
    const ushort_t* __restrict__ w1bf, const float* __restrict__ b1,
    const ushort_t* __restrict__ w2bf, const float* __restrict__ b2,
    const float* __restrict__ W3, const float* __restrict__ b3,
    float* __restrict__ out)
{
    __shared__ ushort_t a1lds[4][16 * 64];
    const int tid  = threadIdx.x;
    const int lane = tid & 63;
    const int e    = lane & 15;
    const int c    = lane >> 4;
    ushort_t* lds  = &a1lds[tid >> 6][0];
    const uint_t swz = (uint_t)((e & 7) << 4);

    bf16x8 w1f[4][4];
    #pragma unroll
    for (int mt = 0; mt < 4; ++mt)
        #pragma unroll
        for (int ks = 0; ks < 4; ++ks)
            w1f[mt][ks] = *(const bf16x8*)(w1bf + (mt * 16 + e) * 128 + ks * 32 + c * 8);

    bf16x8 w2f[2][2];
    #pragma unroll
    for (int mt2 = 0; mt2 < 2; ++mt2)
        #pragma unroll
        for (int ks2 = 0; ks2 < 2; ++ks2)
            w2f[mt2][ks2] = *(const bf16x8*)(w2bf + (mt2 * 16 + e) * 64 + ks2 * 32 + c * 8);

    f32x4 bias1[4];
    #pragma unroll
    for (int mt = 0; mt < 4; ++mt) bias1[mt] = *(const f32x4*)(b1 + mt * 16 + c * 4);
    f32x4 bias2[2];
    #pragma unroll
    for (int mt2 = 0; mt2 < 2; ++mt2) bias2[mt2] = *(const f32x4*)(b2 + mt2 * 16 + c * 4);
    f32x4 w3v[2];
    #pragma unroll
    for (int mt2 = 0; mt2 < 2; ++mt2) w3v[mt2] = *(const f32x4*)(W3 + mt2 * 16 + c * 4);
    const float b3v = b3[0];

    const int nw = (gridDim.x * blockDim.x) >> 6;
    const int NT = NE / 16;

#define LOADZ(T, dst)                                                         \
    {                                                                         \
        int p = (T) * 16 + e;                                                 \
        int ni = ep[p];                                                       \
        int nj = ep[NE + p];                                                  \
        const ushort_t* zi = zbf + (size_t)ni * DOUT;                         \
        const ushort_t* zj = zbf + (size_t)nj * DOUT;                         \
        dst[0] = *(const bf16x8*)(zi + c * 8);                                \
        dst[1] = *(const bf16x8*)(zi + 32 + c * 8);                           \
        dst[2] = *(const bf16x8*)(zj + c * 8);                                \
        dst[3] = *(const bf16x8*)(zj + 32 + c * 8);                           \
    }

#define COMPUTE(T, bfr)                                                       \
    {                                                                         \
        f32x4 acc[4];                                                         \
        _Pragma("unroll")                                                     \
        for (int mt = 0; mt < 4; ++mt) acc[mt] = bias1[mt];                   \
        _Pragma("unroll")                                                     \
        for (int ks = 0; ks < 4; ++ks)                                        \
            _Pragma("unroll")                                                 \
            for (int mt = 0; mt < 4; ++mt)                                    \
                acc[mt] = __builtin_amdgcn_mfma_f32_16x16x32_bf16(            \
                    w1f[mt][ks], bfr[ks], acc[mt], 0, 0, 0);                  \
        _Pragma("unroll")                                                     \
        for (int mt = 0; mt < 4; ++mt) {                                      \
            uint_t lo = pk2bf(fmaxf(acc[mt][0], 0.f), fmaxf(acc[mt][1], 0.f));\
            uint_t hi = pk2bf(fmaxf(acc[mt][2], 0.f), fmaxf(acc[mt][3], 0.f));\
            uint_t off = (uint_t)(e * 128 + mt * 32 + c * 8) ^ swz;           \
            *(uint2*)((char*)lds + off) = make_uint2(lo, hi);                 \
        }                                                                     \
        bf16x8 b2f[2];                                                        \
        _Pragma("unroll")                                                     \
        for (int ks2 = 0; ks2 < 2; ++ks2) {                                   \
            uint_t off = (uint_t)(e * 128 + ks2 * 64 + c * 16) ^ swz;         \
            b2f[ks2] = *(const bf16x8*)((const char*)lds + off);              \
        }                                                                     \
        f32x4 a2[2];                                                          \
        _Pragma("unroll")                                                     \
        for (int mt2 = 0; mt2 < 2; ++mt2) a2[mt2] = bias2[mt2];               \
        _Pragma("unroll")                                                     \
        for (int ks2 = 0; ks2 < 2; ++ks2)                                     \
            _Pragma("unroll")                                                 \
            for (int mt2 = 0; mt2 < 2; ++mt2)                                 \
                a2[mt2] = __builtin_amdgcn_mfma_f32_16x16x32_bf16(            \
                    w2f[mt2][ks2], b2f[ks2], a2[mt2], 0, 0, 0);               \
        float t3 = b3v;                                                       \
        _Pragma("unroll")                                                     \
        for (int mt2 = 0; mt2 < 2; ++mt2)                                     \
            _Pragma("unroll")                                                 \
            for (int r = 0; r < 4; ++r)                                       \
                t3 += fmaxf(a2[mt2][r], 0.f) * w3v[mt2][r];                   \
        t3 += __shfl_xor(t3, 16);                                             \
        t3 += __shfl_xor(t3, 32);                                             \
        if (lane < 16) {                                                      \
            float ex = __expf(-t3);                                           \
            out[(T) * 16 + lane] = __builtin_amdgcn_rcpf(1.f + ex);           \
        }                                                                     \
    }

    bf16x8 zA[4], zB[4], zC[4];
    int ta = (blockIdx.x * blockDim.x + tid) >> 6;    // wave id
    if (ta >= NT) return;
    int tb = ta + nw;
    int tc = tb + nw;
    LOADZ(ta, zA);
    if (tb < NT) LOADZ(tb, zB);
    if (tc < NT) LOADZ(tc, zC);
    while (true) {
        COMPUTE(ta, zA);
        ta += 3 * nw;
        if (ta < NT) LOADZ(ta, zA);
        if (tb >= NT) break;
        COMPUTE(tb, zB);
        tb += 3 * nw;
        if (tb < NT) LOADZ(tb, zB);
        if (tc >= NT) break;
        COMPUTE(tc, zC);
        tc += 3 * nw;
        if (tc < NT) LOADZ(tc, zC);
        if (ta >= NT) break;
    }

#undef LOADZ
#undef COMPUTE
}

// ---------------------------------------------------------------------------
extern "C" void kernel_launch(void* const* d_in, const int* in_sizes, int n_in,
                              void* d_out, int out_size, void* d_ws, size_t ws_size,
                              hipStream_t stream)
{
    const float* x     = (const float*)d_in[0];
    const int*   ei    = (const int*)d_in[1];
    const int*   ep    = (const int*)d_in[2];
    const float* c1_Wl = (const float*)d_in[3];
    const float* c1_bl = (const float*)d_in[4];
    const float* c1_Wr = (const float*)d_in[5];
    const float* bn_g  = (const float*)d_in[6];
    const float* bn_b  = (const float*)d_in[7];
    const float* bn_m  = (const float*)d_in[8];
    const float* bn_v  = (const float*)d_in[9];
    const float* c2_Wl = (const float*)d_in[10];
    const float* c2_bl = (const float*)d_in[11];
    const float* c2_Wr = (const float*)d_in[12];
    const float* e_W1  = (const float*)d_in[13];
    const float* e_b1  = (const float*)d_in[14];
    const float* e_W2  = (const float*)d_in[15];
    const float* e_b2  = (const float*)d_in[16];
    const float* e_W3  = (const float*)d_in[17];
    const float* e_b3  = (const float*)d_in[18];
    float* out = (float*)d_out;

    _Float16* xh    = (_Float16*)d_ws;
    _Float16* hwbuf = xh + (size_t)NN * DIN;
    _Float16* hh    = hwbuf + (size_t)NN * DIN;
    ushort_t* zbf   = (ushort_t*)(hh + (size_t)NN * DHID);
    _Float16* w1cat = (_Float16*)(zbf + (size_t)NN * DOUT);
    _Float16* w2cat = w1cat + 128 * 256;
    ushort_t* w1bf  = (ushort_t*)(w2cat + 64 * 256);
    ushort_t* w2bf  = w1bf + 64 * 128;
    float*    bnsc  = (float*)(w2bf + 32 * 64);
    float*    bnsh  = bnsc + 128;
    int*      deg     = (int*)(bnsh + 128);
    int*      rowptr  = deg + 50052;
    int*      csr_src = rowptr + 50052;
    int*      part    = csr_src + 800000;
    int*      slot    = part + 64;

    hipMemsetAsync(deg, 0, (size_t)50052 * sizeof(int), stream);

    k_deg_xcast<<<6250, 256, 0, stream>>>(ei, deg, slot, x, xh);
    k_scan1_prep<<<50, 256, 0, stream>>>(deg, part,
                                         c1_Wl, c1_Wr, c2_Wl, c2_Wr,
                                         bn_g, bn_b, bn_m, bn_v, e_W1, e_W2,
                                         w1cat, w2cat, w1bf, w2bf, bnsc, bnsh);
    k_scan3<<<49, 256, 0, stream>>>(deg, part, rowptr);
    k_fill <<<3125, 256, 0, stream>>>(ei, rowptr, slot, csr_src);

    k_gconv1<<<3125, 256, 0, stream>>>(xh, rowptr, csr_src, w1cat, c1_bl,
                                       bnsc, bnsh, hh);
    k_hw    <<<3125, 256, 0, stream>>>(hh, w2cat, hwbuf);
    k_gconv2<<<3125, 256, 0, stream>>>(hh, hwbuf, rowptr, csr_src, w2cat, c2_bl, zbf);

    k_edge<<<1024, 256, 0, stream>>>(zbf, ep, w1bf, e_b1, w2bf, e_b2,
                                     e_W3, e_b3, out);
}